// Round 1
// 319.299 us; speedup vs baseline: 1.0237x; 1.0237x over previous
//
#include <hip/hip_runtime.h>
#include <math.h>

#define B_SZ 2
#define L_SZ 2048
#define DMODEL 1024
#define DINNER 2048
#define DSTATE 16
#define DCONV 4
#define DTRANK 64

#define CS 32                    // scan chunk size
#define NCH (L_SZ / CS)          // 64 chunks per batch

typedef float f32x4 __attribute__((ext_vector_type(4)));
typedef __bf16 bf16x8 __attribute__((ext_vector_type(8)));

__device__ __forceinline__ float silu_f(float x) {
    return x / (1.0f + __expf(-x));
}

// fast softplus: max(x,0) + log(1+exp(-|x|)); abs err ~1e-6, branch-free tails
__device__ __forceinline__ float softplus_f(float x) {
    return fmaxf(x, 0.0f) + __logf(1.0f + __expf(-fabsf(x)));
}

// fp32 -> bf16 round-to-nearest-even on raw bits
__device__ __forceinline__ unsigned short f2bf(float x) {
    unsigned int u = __float_as_uint(x);
    u = u + 0x7FFFu + ((u >> 16) & 1u);
    return (unsigned short)(u >> 16);
}

__device__ __forceinline__ float bf2f(unsigned short s) {
    return __uint_as_float(((unsigned int)s) << 16);
}

// async global->LDS DMA, 16B per lane; deposits at base + lane*16B.
__device__ __forceinline__ void gload_lds16(const unsigned short* g, unsigned short* l) {
    __builtin_amdgcn_global_load_lds(
        (const __attribute__((address_space(1))) void*)g,
        (__attribute__((address_space(3))) void*)l, 16, 0, 0);
}

union Pack8 { unsigned short s[8]; uint4 v; };

// Transpose + cast: W[R,C] fp32 -> WT[C,R] bf16. Grid (C/32, R/32), 256 thr.
__global__ __launch_bounds__(256) void transpose_cast(
    const float* __restrict__ W, unsigned short* __restrict__ WT, int R, int C)
{
    __shared__ float t[32][33];
    const int tx = threadIdx.x & 31;
    const int ty = threadIdx.x >> 5;
    const int r0 = blockIdx.y * 32;
    const int c0 = blockIdx.x * 32;
    #pragma unroll
    for (int i = 0; i < 4; i++)
        t[ty + i * 8][tx] = W[(r0 + ty + i * 8) * C + c0 + tx];
    __syncthreads();
    #pragma unroll
    for (int i = 0; i < 4; i++)
        WT[(c0 + ty + i * 8) * R + r0 + tx] = f2bf(t[tx][ty + i * 8]);
}

// cast fp32 -> bf16, 8 elems/thread
__global__ __launch_bounds__(256) void cast_bf16(
    const float* __restrict__ src, unsigned short* __restrict__ dst, int n8)
{
    int i = blockIdx.x * 256 + threadIdx.x;
    if (i >= n8) return;
    const float4 f0 = *(const float4*)(src + i * 8);
    const float4 f1 = *(const float4*)(src + i * 8 + 4);
    Pack8 p;
    p.s[0] = f2bf(f0.x); p.s[1] = f2bf(f0.y); p.s[2] = f2bf(f0.z); p.s[3] = f2bf(f0.w);
    p.s[4] = f2bf(f1.x); p.s[5] = f2bf(f1.y); p.s[6] = f2bf(f1.z); p.s[7] = f2bf(f1.w);
    *(uint4*)(dst + i * 8) = p.v;
}

// ---- bf16 MFMA GEMM, B pre-transposed, global_load_lds staging -------------
// C[M,N] = A[M,K](bf16) @ BT[N,K](bf16)^T, fp32 accumulate.
// BK=64, XOR-swizzled LDS (conflict-free b128 reads, no padding needed).
// Tile 128x128, 4 waves (2x2), 64x64/wave via mfma_f32_16x16x32_bf16.
// Split-K via gridDim.z (Kc multiple of 64). B row clamped to N-1.
template <int ACT, int OBF16>
__global__ __launch_bounds__(256) void gemm_bt_lds(
    const unsigned short* __restrict__ A, const unsigned short* __restrict__ BT,
    void* __restrict__ Cout, const float* __restrict__ bias,
    int M, int N, int K, int lda, int ldb, int ldc, int Kc)
{
    __shared__ unsigned short As[128 * 64];
    __shared__ unsigned short Bs[128 * 64];

    const int tid  = threadIdx.x;
    const int lane = tid & 63;
    const int wave = tid >> 6;
    const int wm   = wave >> 1;
    const int wn   = wave & 1;
    const int row0 = blockIdx.y * 128;
    const int col0 = blockIdx.x * 128;
    const int lq   = lane >> 4;
    const int lm   = lane & 15;
    const int kbeg = blockIdx.z * Kc;

    const int rloc = wave * 32 + (lane >> 3);
    const int sc   = (lane & 7) ^ ((lane >> 3) & 7);
    const unsigned short* gA = A + (size_t)(row0 + rloc) * lda + sc * 8;
    const unsigned short* gBp[4];
    #pragma unroll
    for (int is = 0; is < 4; is++) {
        int br = col0 + rloc + 8 * is;
        if (br > N - 1) br = N - 1;
        gBp[is] = BT + (size_t)br * ldb + sc * 8;
    }
    unsigned short* lA = As + wave * 2048;
    unsigned short* lB = Bs + wave * 2048;

    f32x4 acc[4][4];
    #pragma unroll
    for (int i = 0; i < 4; i++)
        #pragma unroll
        for (int j = 0; j < 4; j++)
            #pragma unroll
            for (int r = 0; r < 4; r++) acc[i][j][r] = 0.0f;

    for (int k0 = kbeg; k0 < kbeg + Kc; k0 += 64) {
        #pragma unroll
        for (int is = 0; is < 4; is++) {
            gload_lds16(gA + (size_t)(8 * is) * lda + k0, lA + is * 512);
            gload_lds16(gBp[is] + k0, lB + is * 512);
        }
        __syncthreads();

        #pragma unroll
        for (int ks = 0; ks < 2; ks++) {
            bf16x8 af[4], bfr[4];
            #pragma unroll
            for (int i = 0; i < 4; i++) {
                int row = wm * 64 + i * 16 + lm;
                af[i] = *(const bf16x8*)&As[row * 64 + (((ks * 4 + lq) ^ (row & 7)) * 8)];
            }
            #pragma unroll
            for (int j = 0; j < 4; j++) {
                int row = wn * 64 + j * 16 + lm;
                bfr[j] = *(const bf16x8*)&Bs[row * 64 + (((ks * 4 + lq) ^ (row & 7)) * 8)];
            }
            #pragma unroll
            for (int i = 0; i < 4; i++)
                #pragma unroll
                for (int j = 0; j < 4; j++)
                    acc[i][j] = __builtin_amdgcn_mfma_f32_16x16x32_bf16(
                        af[i], bfr[j], acc[i][j], 0, 0, 0);
        }
        __syncthreads();
    }

    // epilogue: C/D layout col=lane&15, row=(lane>>4)*4+reg
    #pragma unroll
    for (int i = 0; i < 4; i++) {
        #pragma unroll
        for (int r = 0; r < 4; r++) {
            int row = row0 + wm * 64 + i * 16 + lq * 4 + r;
            #pragma unroll
            for (int j = 0; j < 4; j++) {
                int col = col0 + wn * 64 + j * 16 + lm;
                if (col < N) {
                    float v = acc[i][j][r];
                    if (ACT == 1) v = softplus_f(v + bias[col]);
                    if (OBF16) {
                        unsigned short* Cz = (unsigned short*)Cout +
                            (size_t)blockIdx.z * (size_t)M * ldc;
                        Cz[(size_t)row * ldc + col] = f2bf(v);
                    } else {
                        float* Cz = (float*)Cout +
                            (size_t)blockIdx.z * (size_t)M * ldc;
                        Cz[(size_t)row * ldc + col] = v;
                    }
                }
            }
        }
    }
}

// ---- 256x256 bf16 MFMA GEMM, deep pipeline with counted vmcnt --------------
// 512 threads = 8 waves (2M x 4N), per-wave 128x64 out, BK=64.
// LDS: 2 K-tile double buffer (A 32KB + B 32KB each) = 128KB -> 1 block/CU.
// Staging issued TWO K-tiles ahead via global_load_lds; boundary sync is raw
// s_barrier + s_waitcnt vmcnt(8) (counted, never 0 in steady state), so the
// next-next tile's 8 loads stay in flight across the barrier (T3+T4).
// Pre-swizzled global source + XOR-swizzled ds_read_b128 (conflict-free, T2).
// Requires K >= 128, K % 64 == 0, M % 256 == 0, grid = (M/256)*(N/256) with
// grid % 8 == 0 for the bijective XCD swizzle.
template <int OBF16>
__global__ __launch_bounds__(512, 2) void gemm_bt_256(
    const unsigned short* __restrict__ A, const unsigned short* __restrict__ BT,
    void* __restrict__ Cout, int M, int N, int K, int lda, int ldb, int ldc)
{
    __shared__ unsigned short sm[2][2][256 * 64];   // [buf][A/B][row*64+col]

    const int tid  = threadIdx.x;
    const int lane = tid & 63;
    const int wave = tid >> 6;         // 0..7
    const int wm   = wave >> 2;        // 0..1  M half
    const int wn   = wave & 3;         // 0..3  N quarter
    const int lq   = lane >> 4;
    const int lm   = lane & 15;

    // bijective XCD swizzle: 32 consecutive tile-ids per XCD -> contiguous
    // M-panels per XCD L2 (A reuse). gridDim.x % 8 == 0 guaranteed by caller.
    const int cpx = gridDim.x >> 3;
    const int ti  = (blockIdx.x & 7) * cpx + (blockIdx.x >> 3);
    const int nbx = N >> 8;
    const int bx  = ti % nbx;
    const int by  = ti / nbx;
    const int row0 = by * 256;
    const int col0 = bx * 256;

    // staging: 8 gloads/wave per K-tile (4 for A, 4 for B). Call a covers rows
    // a*64..a*64+63; thread t -> row rA=t>>3, 16B at group sc=(t&7)^(rA&7).
    // Linear LDS dest + pre-swizzled source == swizzled store (m201 pattern).
    const int rA = tid >> 3;
    const int sc = (tid & 7) ^ (rA & 7);
    const unsigned short* gA = A + (size_t)(row0 + rA) * lda + sc * 8;
    const unsigned short* gB[4];
    #pragma unroll
    for (int a = 0; a < 4; a++) {
        int br = col0 + a * 64 + rA;
        if (br > N - 1) br = N - 1;
        gB[a] = BT + (size_t)br * ldb + sc * 8;
    }

    auto STAGE = [&](int bsel, int kk) {
        #pragma unroll
        for (int a = 0; a < 4; a++) {
            gload_lds16(gA + (size_t)(a * 64) * lda + kk,
                        &sm[bsel][0][a * 4096 + wave * 512]);
            gload_lds16(gB[a] + kk,
                        &sm[bsel][1][a * 4096 + wave * 512]);
        }
    };

    f32x4 acc[8][4];
    #pragma unroll
    for (int i = 0; i < 8; i++)
        #pragma unroll
        for (int j = 0; j < 4; j++)
            #pragma unroll
            for (int r = 0; r < 4; r++) acc[i][j][r] = 0.0f;

    const int NT = K >> 6;
    STAGE(0, 0);
    STAGE(1, 64);

    for (int t = 0; t < NT; ++t) {
        // leading edge: oldest K-tile's 8 loads retired; newer 8 stay in flight
        if (t < NT - 1) {
            asm volatile("s_waitcnt vmcnt(8)" ::: "memory");
        } else {
            asm volatile("s_waitcnt vmcnt(0)" ::: "memory");
        }
        __builtin_amdgcn_s_barrier();
        __builtin_amdgcn_sched_barrier(0);

        const int b = t & 1;
        #pragma unroll
        for (int ks = 0; ks < 2; ks++) {
            bf16x8 af[8], bq[4];
            #pragma unroll
            for (int i = 0; i < 8; i++) {
                int row = wm * 128 + i * 16 + lm;
                af[i] = *(const bf16x8*)&sm[b][0][row * 64 +
                            (((ks * 4 + lq) ^ (row & 7)) * 8)];
            }
            #pragma unroll
            for (int j = 0; j < 4; j++) {
                int row = wn * 64 + j * 16 + lm;
                bq[j] = *(const bf16x8*)&sm[b][1][row * 64 +
                            (((ks * 4 + lq) ^ (row & 7)) * 8)];
            }
            #pragma unroll
            for (int i = 0; i < 8; i++)
                #pragma unroll
                for (int j = 0; j < 4; j++)
                    acc[i][j] = __builtin_amdgcn_mfma_f32_16x16x32_bf16(
                        af[i], bq[j], acc[i][j], 0, 0, 0);
        }

        // trailing edge: my ds_reads retired, all waves done reading buf b,
        // then overwrite buf b with K-tile t+2 (stays in flight past next barrier)
        asm volatile("s_waitcnt lgkmcnt(0)" ::: "memory");
        __builtin_amdgcn_sched_barrier(0);
        __builtin_amdgcn_s_barrier();
        __builtin_amdgcn_sched_barrier(0);
        if (t + 2 < NT) STAGE(b, (t + 2) * 64);
    }

    // epilogue: C/D layout col=lane&15, row=(lane>>4)*4+reg
    #pragma unroll
    for (int i = 0; i < 8; i++) {
        #pragma unroll
        for (int r = 0; r < 4; r++) {
            int row = row0 + wm * 128 + i * 16 + lq * 4 + r;
            #pragma unroll
            for (int j = 0; j < 4; j++) {
                int col = col0 + wn * 64 + j * 16 + lm;
                if (col < N) {
                    float v = acc[i][j][r];
                    if (OBF16)
                        ((unsigned short*)Cout)[(size_t)row * ldc + col] = f2bf(v);
                    else
                        ((float*)Cout)[(size_t)row * ldc + col] = v;
                }
            }
        }
    }
}

// Sum nsplit partial C buffers; also emit bf16 copy of cols<64 (dt_lo).
__global__ __launch_bounds__(256) void reduce_splitk(
    const float* __restrict__ part, float* __restrict__ C,
    unsigned short* __restrict__ dtlo16, int n, int nsplit)
{
    int i = blockIdx.x * 256 + threadIdx.x;
    if (i >= n) return;
    float s = 0.0f;
    for (int z = 0; z < nsplit; z++) s += part[(size_t)z * n + i];
    C[i] = s;
    int row = i / 96;
    int col = i - row * 96;
    if (col < DTRANK) dtlo16[row * DTRANK + col] = f2bf(s);
}

// conv + silu, register-rolling window along l. Reads bf16 xz (cols 0..2048),
// emits bf16 xc16. grid (8, 64, 2).
__global__ __launch_bounds__(256) void conv_silu_v2(
    const unsigned short* __restrict__ xz16, const float* __restrict__ conv_w,
    const float* __restrict__ conv_b, unsigned short* __restrict__ xc16)
{
    const int tid = threadIdx.x;
    const int d   = blockIdx.x * 256 + tid;
    const int l0  = blockIdx.y * 32;
    const int b   = blockIdx.z;
    const float4 w  = *(const float4*)(conv_w + d * 4);
    const float bias = conv_b[d];
    const int t0 = b * L_SZ + l0;
    const unsigned short* src = xz16 + (size_t)t0 * 4096 + d;

    float r0, r1, r2;
    if (l0 == 0) {
        r0 = r1 = r2 = 0.0f;
    } else {
        r0 = bf2f(src[-3 * 4096]);
        r1 = bf2f(src[-2 * 4096]);
        r2 = bf2f(src[-1 * 4096]);
    }
    #pragma unroll 4
    for (int l = 0; l < 32; l++) {
        float r3 = bf2f(src[(size_t)l * 4096]);
        float acc = bias + r0 * w.x + r1 * w.y + r2 * w.z + r3 * w.w;
        xc16[(size_t)(t0 + l) * DINNER + d] = f2bf(silu_f(acc));
        r0 = r1; r1 = r2; r2 = r3;
    }
}

// ---- Chunked parallel selective scan (CS=32, 1024 blocks) -------------------
// grid: B * NCH * 8 = 2*64*8 = 1024; db=blk&7, c=(blk>>3)&63, b=blk>>9.
__global__ __launch_bounds__(256) void scan_pass1(
    const unsigned short* __restrict__ xc16, const float* __restrict__ delta,
    const float* __restrict__ dbc, const float* __restrict__ A_log,
    float* __restrict__ P, float* __restrict__ E)
{
    __shared__ float Bs[CS * DSTATE];
    const int tid = threadIdx.x;
    const int db  = blockIdx.x & 7;
    const int c   = (blockIdx.x >> 3) & (NCH - 1);
    const int b   = blockIdx.x >> 9;
    const int d   = db * 256 + tid;
    const int t0  = b * L_SZ + c * CS;

    for (int idx = tid; idx < CS * DSTATE; idx += 256) {
        int step = idx >> 4, i = idx & 15;
        Bs[idx] = dbc[(t0 + step) * 96 + DTRANK + i];
    }

    float A[DSTATE], Er[DSTATE];
    #pragma unroll
    for (int s = 0; s < DSTATE; s++) {
        A[s]  = -__expf(A_log[d * DSTATE + s]);
        Er[s] = 0.0f;
    }
    float sd = 0.0f;
    __syncthreads();

    for (int l = 0; l < CS; l++) {
        const int t = t0 + l;
        float dv = delta[t * DINNER + d];
        float uv = bf2f(xc16[(size_t)t * DINNER + d]);
        float du = dv * uv;
        sd += dv;
        #pragma unroll
        for (int s = 0; s < DSTATE; s++) {
            float dA = __expf(dv * A[s]);
            Er[s] = dA * Er[s] + du * Bs[l * DSTATE + s];
        }
    }

    const long long o = ((long long)((b * NCH + c) * DINNER) + d) * DSTATE;
    #pragma unroll
    for (int s = 0; s < DSTATE; s++) {
        P[o + s] = __expf(A[s] * sd);
        E[o + s] = Er[s];
    }
}

__global__ __launch_bounds__(256) void scan_pass2(
    const float* __restrict__ P, float* __restrict__ E)
{
    const int gid  = blockIdx.x * 256 + threadIdx.x;
    const int b    = gid >> 15;
    const int rest = gid & 32767;
    float h = 0.0f;
    for (int c = 0; c < NCH; c++) {
        const long long idx = (long long)(b * NCH + c) * (DINNER * DSTATE) + rest;
        float p = P[idx];
        float e = E[idx];
        E[idx] = h;
        h = p * h + e;
    }
}

// pass3: emit y in bf16, fused silu(z) gate (z from bf16 xz cols 2048..4096).
__global__ __launch_bounds__(256) void scan_pass3(
    const unsigned short* __restrict__ xc16, const float* __restrict__ delta,
    const float* __restrict__ dbc, const float* __restrict__ A_log,
    const float* __restrict__ D_skip, const float* __restrict__ Hin,
    const unsigned short* __restrict__ xz16, unsigned short* __restrict__ y16)
{
    __shared__ float BCs[CS * 2 * DSTATE];
    const int tid = threadIdx.x;
    const int db  = blockIdx.x & 7;
    const int c   = (blockIdx.x >> 3) & (NCH - 1);
    const int b   = blockIdx.x >> 9;
    const int d   = db * 256 + tid;
    const int t0  = b * L_SZ + c * CS;

    for (int idx = tid; idx < CS * 2 * DSTATE; idx += 256) {
        int step = idx >> 5, i = idx & 31;
        BCs[idx] = dbc[(t0 + step) * 96 + DTRANK + i];
    }

    float A[DSTATE], h[DSTATE];
    const long long o = ((long long)((b * NCH + c) * DINNER) + d) * DSTATE;
    #pragma unroll
    for (int s = 0; s < DSTATE; s++) {
        A[s] = -__expf(A_log[d * DSTATE + s]);
        h[s] = Hin[o + s];
    }
    const float Dv = D_skip[d];
    __syncthreads();

    for (int l = 0; l < CS; l++) {
        const int t = t0 + l;
        float dv = delta[t * DINNER + d];
        float uv = bf2f(xc16[(size_t)t * DINNER + d]);
        float du = dv * uv;
        float yv = 0.0f;
        #pragma unroll
        for (int s = 0; s < DSTATE; s++) {
            float dA = __expf(dv * A[s]);
            h[s] = dA * h[s] + du * BCs[l * 32 + s];
            yv  += h[s] * BCs[l * 32 + DSTATE + s];
        }
        float z = bf2f(xz16[(size_t)t * 4096 + DINNER + d]);
        y16[t * DINNER + d] = f2bf((uv * Dv + yv) * silu_f(z));
    }
}

extern "C" void kernel_launch(void* const* d_in, const int* in_sizes, int n_in,
                              void* d_out, int out_size, void* d_ws, size_t ws_size,
                              hipStream_t stream) {
    const float* x       = (const float*)d_in[0];
    const float* W_in    = (const float*)d_in[1];
    const float* conv_w  = (const float*)d_in[2];
    const float* conv_b  = (const float*)d_in[3];
    const float* W_xproj = (const float*)d_in[4];
    const float* W_dt    = (const float*)d_in[5];
    const float* b_dt    = (const float*)d_in[6];
    const float* A_log   = (const float*)d_in[7];
    const float* D_skip  = (const float*)d_in[8];
    const float* W_out   = (const float*)d_in[9];
    float* out = (float*)d_out;

    // workspace layout, float units (141 MB). Aliases (dead-before-reuse):
    //   parts (dead after reduce) shares Pbuf (written at pass1)
    //   x16 (dead after gemm1)    shares yb16 (written at pass3)
    float* ws = (float*)d_ws;
    unsigned short* xz16   = (unsigned short*)ws;              // [0 .. 8388608) f
    unsigned short* xc16   = (unsigned short*)(ws +  8388608); // [.. 12582912) f
    float* dbc             = ws + 12582912;                    // [.. 12976128) f
    unsigned short* dtlo16 = (unsigned short*)(ws + 12976128); // [.. 13107200) f
    float* delta           = ws + 13107200;                    // [.. 21495808) f
    float* Ebuf            = ws + 21495808;                    // [.. 25690112) f : 2*64*2048*16
    float* Pbuf            = ws + 25690112;                    // [.. 29884416) f : 2*64*2048*16
    float* parts           = Pbuf;                             //   alias, 3145728 f < 4194304 ✓
    unsigned short* yb16   = (unsigned short*)(ws + 29884416); // [.. 31981568) f
    unsigned short* x16    = yb16;                             //   alias
    unsigned short* W_inT    = (unsigned short*)(ws + 31981568); // [.. 34078720) f
    unsigned short* W_xprojT = (unsigned short*)(ws + 34078720); // [.. 34177024) f
    unsigned short* W_dtT    = (unsigned short*)(ws + 34177024); // [.. 34242560) f
    unsigned short* W_outT   = (unsigned short*)(ws + 34242560); // [.. 35291136) f

    const int MT = 4096;  // B*L tokens

    transpose_cast<<<dim3(128, 32), 256, 0, stream>>>(W_in,    W_inT,    1024, 4096);
    transpose_cast<<<dim3(  3, 64), 256, 0, stream>>>(W_xproj, W_xprojT, 2048,   96);
    transpose_cast<<<dim3( 64,  2), 256, 0, stream>>>(W_dt,    W_dtT,      64, 2048);
    transpose_cast<<<dim3( 32, 64), 256, 0, stream>>>(W_out,   W_outT,   2048, 1024);
    cast_bf16<<<dim3(2048), 256, 0, stream>>>(x, x16, 524288);

    // 1) xz = x @ W_in              (4096 x 4096, K=1024) -> bf16
    //    256^2 tile deep-pipeline kernel: grid 16x16 = 256 blocks = 1/CU
    gemm_bt_256<1><<<dim3(256), 512, 0, stream>>>(
        x16, W_inT, xz16, MT, 4096, 1024, 1024, 1024, 4096);

    // 2) xc16 = silu(causal_dwconv(xin) + b)
    conv_silu_v2<<<dim3(8, 64, 2), 256, 0, stream>>>(xz16, conv_w, conv_b, xc16);

    // 3) dbc = xc @ W_xproj         (4096 x 96, K=2048) — split-K x8
    gemm_bt_lds<0, 0><<<dim3(1, 32, 8), 256, 0, stream>>>(
        xc16, W_xprojT, parts, nullptr, MT, 96, 2048, 2048, 2048, 96, 256);
    reduce_splitk<<<dim3(1536), 256, 0, stream>>>(parts, dbc, dtlo16, MT * 96, 8);

    // 4) delta = softplus(dt_lo @ W_dt + b_dt)  (4096 x 2048, K=64) — fast softplus
    gemm_bt_lds<1, 0><<<dim3(16, 32), 256, 0, stream>>>(
        dtlo16, W_dtT, delta, b_dt, MT, 2048, 64, 64, 64, 2048, 64);

    // 5) chunked selective scan + fused gate (bf16 y out)
    scan_pass1<<<dim3(1024), 256, 0, stream>>>(xc16, delta, dbc, A_log, Pbuf, Ebuf);
    scan_pass2<<<dim3(256), 256, 0, stream>>>(Pbuf, Ebuf);
    scan_pass3<<<dim3(1024), 256, 0, stream>>>(xc16, delta, dbc, A_log, D_skip,
                                               Ebuf, xz16, yb16);

    // 6) out = y @ W_out            (4096 x 1024, K=2048)
    gemm_bt_lds<0, 0><<<dim3(8, 32), 256, 0, stream>>>(
        yb16, W_outT, out, nullptr, MT, 1024, 2048, 2048, 2048, 1024, 2048);
}

// Round 3
// 310.858 us; speedup vs baseline: 1.0515x; 1.0272x over previous
//
#include <hip/hip_runtime.h>
#include <math.h>

#define B_SZ 2
#define L_SZ 2048
#define DMODEL 1024
#define DINNER 2048
#define DSTATE 16
#define DCONV 4
#define DTRANK 64

#define CS 32                    // scan chunk size
#define NCH (L_SZ / CS)          // 64 chunks per batch

typedef float f32x4 __attribute__((ext_vector_type(4)));
typedef __bf16 bf16x8 __attribute__((ext_vector_type(8)));

__device__ __forceinline__ float silu_f(float x) {
    return x / (1.0f + __expf(-x));
}

// fast softplus: max(x,0) + log(1+exp(-|x|)); abs err ~1e-6, branch-free tails
__device__ __forceinline__ float softplus_f(float x) {
    return fmaxf(x, 0.0f) + __logf(1.0f + __expf(-fabsf(x)));
}

// fp32 -> bf16 round-to-nearest-even on raw bits
__device__ __forceinline__ unsigned short f2bf(float x) {
    unsigned int u = __float_as_uint(x);
    u = u + 0x7FFFu + ((u >> 16) & 1u);
    return (unsigned short)(u >> 16);
}

__device__ __forceinline__ float bf2f(unsigned short s) {
    return __uint_as_float(((unsigned int)s) << 16);
}

// async global->LDS DMA, 16B per lane; deposits at base + lane*16B.
__device__ __forceinline__ void gload_lds16(const unsigned short* g, unsigned short* l) {
    __builtin_amdgcn_global_load_lds(
        (const __attribute__((address_space(1))) void*)g,
        (__attribute__((address_space(3))) void*)l, 16, 0, 0);
}

union Pack8 { unsigned short s[8]; uint4 v; };

// Transpose + cast: W[R,C] fp32 -> WT[C,R] bf16. Grid (C/32, R/32), 256 thr.
__global__ __launch_bounds__(256) void transpose_cast(
    const float* __restrict__ W, unsigned short* __restrict__ WT, int R, int C)
{
    __shared__ float t[32][33];
    const int tx = threadIdx.x & 31;
    const int ty = threadIdx.x >> 5;
    const int r0 = blockIdx.y * 32;
    const int c0 = blockIdx.x * 32;
    #pragma unroll
    for (int i = 0; i < 4; i++)
        t[ty + i * 8][tx] = W[(r0 + ty + i * 8) * C + c0 + tx];
    __syncthreads();
    #pragma unroll
    for (int i = 0; i < 4; i++)
        WT[(c0 + ty + i * 8) * R + r0 + tx] = f2bf(t[tx][ty + i * 8]);
}

// cast fp32 -> bf16, 8 elems/thread
__global__ __launch_bounds__(256) void cast_bf16(
    const float* __restrict__ src, unsigned short* __restrict__ dst, int n8)
{
    int i = blockIdx.x * 256 + threadIdx.x;
    if (i >= n8) return;
    const float4 f0 = *(const float4*)(src + i * 8);
    const float4 f1 = *(const float4*)(src + i * 8 + 4);
    Pack8 p;
    p.s[0] = f2bf(f0.x); p.s[1] = f2bf(f0.y); p.s[2] = f2bf(f0.z); p.s[3] = f2bf(f0.w);
    p.s[4] = f2bf(f1.x); p.s[5] = f2bf(f1.y); p.s[6] = f2bf(f1.z); p.s[7] = f2bf(f1.w);
    *(uint4*)(dst + i * 8) = p.v;
}

// ---- bf16 MFMA GEMM, B pre-transposed, global_load_lds staging -------------
// (128x128 2-phase kernel, kept for the small GEMMs 3 and 4.)
template <int ACT, int OBF16>
__global__ __launch_bounds__(256) void gemm_bt_lds(
    const unsigned short* __restrict__ A, const unsigned short* __restrict__ BT,
    void* __restrict__ Cout, const float* __restrict__ bias,
    int M, int N, int K, int lda, int ldb, int ldc, int Kc)
{
    __shared__ unsigned short As[128 * 64];
    __shared__ unsigned short Bs[128 * 64];

    const int tid  = threadIdx.x;
    const int lane = tid & 63;
    const int wave = tid >> 6;
    const int wm   = wave >> 1;
    const int wn   = wave & 1;
    const int row0 = blockIdx.y * 128;
    const int col0 = blockIdx.x * 128;
    const int lq   = lane >> 4;
    const int lm   = lane & 15;
    const int kbeg = blockIdx.z * Kc;

    const int rloc = wave * 32 + (lane >> 3);
    const int sc   = (lane & 7) ^ ((lane >> 3) & 7);
    const unsigned short* gA = A + (size_t)(row0 + rloc) * lda + sc * 8;
    const unsigned short* gBp[4];
    #pragma unroll
    for (int is = 0; is < 4; is++) {
        int br = col0 + rloc + 8 * is;
        if (br > N - 1) br = N - 1;
        gBp[is] = BT + (size_t)br * ldb + sc * 8;
    }
    unsigned short* lA = As + wave * 2048;
    unsigned short* lB = Bs + wave * 2048;

    f32x4 acc[4][4];
    #pragma unroll
    for (int i = 0; i < 4; i++)
        #pragma unroll
        for (int j = 0; j < 4; j++)
            #pragma unroll
            for (int r = 0; r < 4; r++) acc[i][j][r] = 0.0f;

    for (int k0 = kbeg; k0 < kbeg + Kc; k0 += 64) {
        #pragma unroll
        for (int is = 0; is < 4; is++) {
            gload_lds16(gA + (size_t)(8 * is) * lda + k0, lA + is * 512);
            gload_lds16(gBp[is] + k0, lB + is * 512);
        }
        __syncthreads();

        #pragma unroll
        for (int ks = 0; ks < 2; ks++) {
            bf16x8 af[4], bfr[4];
            #pragma unroll
            for (int i = 0; i < 4; i++) {
                int row = wm * 64 + i * 16 + lm;
                af[i] = *(const bf16x8*)&As[row * 64 + (((ks * 4 + lq) ^ (row & 7)) * 8)];
            }
            #pragma unroll
            for (int j = 0; j < 4; j++) {
                int row = wn * 64 + j * 16 + lm;
                bfr[j] = *(const bf16x8*)&Bs[row * 64 + (((ks * 4 + lq) ^ (row & 7)) * 8)];
            }
            #pragma unroll
            for (int i = 0; i < 4; i++)
                #pragma unroll
                for (int j = 0; j < 4; j++)
                    acc[i][j] = __builtin_amdgcn_mfma_f32_16x16x32_bf16(
                        af[i], bfr[j], acc[i][j], 0, 0, 0);
        }
        __syncthreads();
    }

    // epilogue: C/D layout col=lane&15, row=(lane>>4)*4+reg
    #pragma unroll
    for (int i = 0; i < 4; i++) {
        #pragma unroll
        for (int r = 0; r < 4; r++) {
            int row = row0 + wm * 64 + i * 16 + lq * 4 + r;
            #pragma unroll
            for (int j = 0; j < 4; j++) {
                int col = col0 + wn * 64 + j * 16 + lm;
                if (col < N) {
                    float v = acc[i][j][r];
                    if (ACT == 1) v = softplus_f(v + bias[col]);
                    if (OBF16) {
                        unsigned short* Cz = (unsigned short*)Cout +
                            (size_t)blockIdx.z * (size_t)M * ldc;
                        Cz[(size_t)row * ldc + col] = f2bf(v);
                    } else {
                        float* Cz = (float*)Cout +
                            (size_t)blockIdx.z * (size_t)M * ldc;
                        Cz[(size_t)row * ldc + col] = v;
                    }
                }
            }
        }
    }
}

// ---- 256x256 8-phase bf16 GEMM (m201-style), counted vmcnt + setprio -------
// 512 thr = 8 waves (2M x 4N), per-wave 128x64 out, BK=64, NT = Kc/64 K-tiles.
// LDS 128KB: sm[buf][A|B][unit:4][64x64 bf16]. Unit u = 64 rows (A: tile rows
// u*64.., B: tile cols u*64..). XOR-swizzle: LDS[r][g] = global[r][g^(r&7)],
// staged linearly via pre-swizzled source (both-sides-or-neither, rule #21).
//
// Per K-tile: 4 phases; phase q computes i-pair (2q,2q+1) x 4j x both ks
// (16 MFMA). Reads per wave: af 4xb128/phase, bq 8xb128 at q=0 (lives all
// tile). B units are dead after ph0; A units (rows q*32 of each half) after
// ph1/ph3 -> staging calendar (per tile t, 2 units/phase):
//   q0: (t+1).a1,a3   q1: (t+1).b2,b3   [other buffer, always safe]
//   q2: (t+2).b0,b1   q3: (t+2).a0,a2   [this buffer, regions dead]
// Issue order makes one vmcnt(4) per K-tile retire exactly tile t's 8 units
// (vmcnt(0) only at t=NT-1). Units are staged 5-6 phases (~>900cy) ahead.
template <int OBF16>
__global__ __launch_bounds__(512, 2) void gemm_8ph(
    const unsigned short* __restrict__ A, const unsigned short* __restrict__ BT,
    void* __restrict__ Cout, int M, int N, int lda, int ldb, int ldc, int Kc)
{
    __shared__ unsigned short sm[2][2][4][64 * 64];

    const int tid  = threadIdx.x;
    const int lane = tid & 63;
    const int wave = tid >> 6;         // 0..7
    const int wm   = wave >> 2;        // 0..1  (128-row half)
    const int wn   = wave & 3;         // 0..3  (64-col quarter)
    const int lq   = lane >> 4;
    const int lm   = lane & 15;

    // bijective XCD swizzle (gridDim.x % 8 == 0 guaranteed by caller)
    const int cpx = gridDim.x >> 3;
    const int ti  = (blockIdx.x & 7) * cpx + (blockIdx.x >> 3);
    const int nbx = N >> 8;
    const int row0 = (ti / nbx) * 256;
    const int col0 = (ti % nbx) * 256;
    const int kbeg = blockIdx.z * Kc;

    // staging: one gload per thread per 64-row unit (512 thr x 16B = 8KB)
    const int r  = tid >> 3;                 // row within unit, 0..63
    const int sc = (tid & 7) ^ (r & 7);      // pre-swizzled source group
    const unsigned short* gA = A + (size_t)(row0 + r) * lda + sc * 8 + kbeg;
    const unsigned short* gB[4];
    #pragma unroll
    for (int u = 0; u < 4; u++) {
        int br = col0 + u * 64 + r;
        if (br > N - 1) br = N - 1;
        gB[u] = BT + (size_t)br * ldb + sc * 8 + kbeg;
    }

    #define STA(bsel, u, kk) gload_lds16(gA + (size_t)((u) * 64) * lda + (kk), \
                                         &sm[bsel][0][u][wave * 512])
    #define STB(bsel, u, kk) gload_lds16(gB[u] + (kk), &sm[bsel][1][u][wave * 512])

    f32x4 acc[8][4];
    #pragma unroll
    for (int i = 0; i < 8; i++)
        #pragma unroll
        for (int j = 0; j < 4; j++)
            #pragma unroll
            for (int rr = 0; rr < 4; rr++) acc[i][j][rr] = 0.0f;

    const int NT = Kc >> 6;
    // prologue, exact issue order (oldest->newest) matched to vmcnt(4) math:
    // [0.b0 0.b1][0.a0 0.a2][0.a1 0.a3][0.b2 0.b3][1.b0 1.b1][1.a0 1.a2]
    STB(0, 0, 0); STB(0, 1, 0); STA(0, 0, 0); STA(0, 2, 0);
    STA(0, 1, 0); STA(0, 3, 0); STB(0, 2, 0); STB(0, 3, 0);
    if (NT > 1) { STB(1, 0, 64); STB(1, 1, 64); STA(1, 0, 64); STA(1, 2, 64); }

    bf16x8 bq[4][2];

    for (int t = 0; t < NT; ++t) {
        const int b   = t & 1;
        const int kk1 = (t + 1) * 64;
        const int kk2 = (t + 2) * 64;

        if (t == NT - 1) asm volatile("s_waitcnt vmcnt(0)" ::: "memory");
        else             asm volatile("s_waitcnt vmcnt(4)" ::: "memory");
        __builtin_amdgcn_s_barrier();
        __builtin_amdgcn_sched_barrier(0);

        #pragma unroll
        for (int q = 0; q < 4; ++q) {
            bf16x8 af2[2][2];
            #pragma unroll
            for (int ii = 0; ii < 2; ii++) {
                int br = wm * 128 + (2 * q + ii) * 16 + lm;
                #pragma unroll
                for (int ks = 0; ks < 2; ks++)
                    af2[ii][ks] = *(const bf16x8*)&sm[b][0][br >> 6]
                        [(br & 63) * 64 + (((ks * 4 + lq) ^ (br & 7)) * 8)];
            }
            if (q == 0) {
                #pragma unroll
                for (int j = 0; j < 4; j++) {
                    int br = wn * 64 + j * 16 + lm;
                    #pragma unroll
                    for (int ks = 0; ks < 2; ks++)
                        bq[j][ks] = *(const bf16x8*)&sm[b][1][br >> 6]
                            [(br & 63) * 64 + (((ks * 4 + lq) ^ (br & 7)) * 8)];
                }
            }
            // staging calendar (2 units / phase)
            if (q == 0 && t + 1 < NT) { STA(b ^ 1, 1, kk1); STA(b ^ 1, 3, kk1); }
            if (q == 1 && t + 1 < NT) { STB(b ^ 1, 2, kk1); STB(b ^ 1, 3, kk1); }
            if (q == 2 && t + 2 < NT) { STB(b, 0, kk2); STB(b, 1, kk2); }
            if (q == 3 && t + 2 < NT) { STA(b, 0, kk2); STA(b, 2, kk2); }

            asm volatile("s_waitcnt lgkmcnt(0)" ::: "memory");
            __builtin_amdgcn_sched_barrier(0);
            __builtin_amdgcn_s_setprio(1);
            #pragma unroll
            for (int ii = 0; ii < 2; ii++)
                #pragma unroll
                for (int j = 0; j < 4; j++) {
                    acc[2 * q + ii][j] = __builtin_amdgcn_mfma_f32_16x16x32_bf16(
                        af2[ii][0], bq[j][0], acc[2 * q + ii][j], 0, 0, 0);
                    acc[2 * q + ii][j] = __builtin_amdgcn_mfma_f32_16x16x32_bf16(
                        af2[ii][1], bq[j][1], acc[2 * q + ii][j], 0, 0, 0);
                }
            __builtin_amdgcn_s_setprio(0);
            __builtin_amdgcn_sched_barrier(0);
            if (q < 3) {
                __builtin_amdgcn_s_barrier();
                __builtin_amdgcn_sched_barrier(0);
            }
        }
    }
    #undef STA
    #undef STB

    // epilogue: C/D layout col=lane&15, row=(lane>>4)*4+reg
    const size_t zoff = (size_t)blockIdx.z * (size_t)M * ldc;
    #pragma unroll
    for (int i = 0; i < 8; i++) {
        #pragma unroll
        for (int rr = 0; rr < 4; rr++) {
            int row = row0 + wm * 128 + i * 16 + lq * 4 + rr;
            #pragma unroll
            for (int j = 0; j < 4; j++) {
                int col = col0 + wn * 64 + j * 16 + lm;
                if (col < N) {
                    float v = acc[i][j][rr];
                    if (OBF16)
                        ((unsigned short*)Cout)[(size_t)row * ldc + col] = f2bf(v);
                    else
                        ((float*)Cout)[zoff + (size_t)row * ldc + col] = v;
                }
            }
        }
    }
}

// Sum nsplit partial C buffers; also emit bf16 copy of cols<64 (dt_lo).
__global__ __launch_bounds__(256) void reduce_splitk(
    const float* __restrict__ part, float* __restrict__ C,
    unsigned short* __restrict__ dtlo16, int n, int nsplit)
{
    int i = blockIdx.x * 256 + threadIdx.x;
    if (i >= n) return;
    float s = 0.0f;
    for (int z = 0; z < nsplit; z++) s += part[(size_t)z * n + i];
    C[i] = s;
    int row = i / 96;
    int col = i - row * 96;
    if (col < DTRANK) dtlo16[row * DTRANK + col] = f2bf(s);
}

// Sum 4 fp32 partials, vectorized. n4 = total_floats/4.
__global__ __launch_bounds__(256) void reduce4(
    const float* __restrict__ part, float* __restrict__ out, int n4)
{
    int i = blockIdx.x * 256 + threadIdx.x;
    if (i >= n4) return;
    const f32x4* p = (const f32x4*)part;
    f32x4 s = p[i];
    s += p[i + n4];
    s += p[i + 2 * n4];
    s += p[i + 3 * n4];
    ((f32x4*)out)[i] = s;
}

// conv + silu, register-rolling window along l. Reads bf16 xz (cols 0..2048),
// emits bf16 xc16. grid (8, 64, 2).
__global__ __launch_bounds__(256) void conv_silu_v2(
    const unsigned short* __restrict__ xz16, const float* __restrict__ conv_w,
    const float* __restrict__ conv_b, unsigned short* __restrict__ xc16)
{
    const int tid = threadIdx.x;
    const int d   = blockIdx.x * 256 + tid;
    const int l0  = blockIdx.y * 32;
    const int b   = blockIdx.z;
    const float4 w  = *(const float4*)(conv_w + d * 4);
    const float bias = conv_b[d];
    const int t0 = b * L_SZ + l0;
    const unsigned short* src = xz16 + (size_t)t0 * 4096 + d;

    float r0, r1, r2;
    if (l0 == 0) {
        r0 = r1 = r2 = 0.0f;
    } else {
        r0 = bf2f(src[-3 * 4096]);
        r1 = bf2f(src[-2 * 4096]);
        r2 = bf2f(src[-1 * 4096]);
    }
    #pragma unroll 4
    for (int l = 0; l < 32; l++) {
        float r3 = bf2f(src[(size_t)l * 4096]);
        float acc = bias + r0 * w.x + r1 * w.y + r2 * w.z + r3 * w.w;
        xc16[(size_t)(t0 + l) * DINNER + d] = f2bf(silu_f(acc));
        r0 = r1; r1 = r2; r2 = r3;
    }
}

// ---- Chunked parallel selective scan (CS=32, 1024 blocks) -------------------
// grid: B * NCH * 8 = 2*64*8 = 1024; db=blk&7, c=(blk>>3)&63, b=blk>>9.
// 4-step software pipeline: prefetch next group's delta/xc(/z) into registers
// while the 16-state recurrence runs on the current group (latency hiding).
__global__ __launch_bounds__(256) void scan_pass1(
    const unsigned short* __restrict__ xc16, const float* __restrict__ delta,
    const float* __restrict__ dbc, const float* __restrict__ A_log,
    float* __restrict__ P, float* __restrict__ E)
{
    __shared__ float Bs[CS * DSTATE];
    const int tid = threadIdx.x;
    const int db  = blockIdx.x & 7;
    const int c   = (blockIdx.x >> 3) & (NCH - 1);
    const int b   = blockIdx.x >> 9;
    const int d   = db * 256 + tid;
    const int t0  = b * L_SZ + c * CS;

    for (int idx = tid; idx < CS * DSTATE; idx += 256) {
        int step = idx >> 4, i = idx & 15;
        Bs[idx] = dbc[(t0 + step) * 96 + DTRANK + i];
    }

    float A[DSTATE], Er[DSTATE];
    #pragma unroll
    for (int s = 0; s < DSTATE; s++) {
        A[s]  = -__expf(A_log[d * DSTATE + s]);
        Er[s] = 0.0f;
    }
    float sd = 0.0f;

    const float* dp = delta + (size_t)t0 * DINNER + d;
    const unsigned short* up = xc16 + (size_t)t0 * DINNER + d;

    float dv[4], uv[4];
    #pragma unroll
    for (int q = 0; q < 4; q++) {
        dv[q] = dp[(size_t)q * DINNER];
        uv[q] = bf2f(up[(size_t)q * DINNER]);
    }
    __syncthreads();

    for (int lo = 0; lo < CS; lo += 4) {
        float nd[4], nu[4];
        if (lo + 4 < CS) {
            #pragma unroll
            for (int q = 0; q < 4; q++) {
                nd[q] = dp[(size_t)(lo + 4 + q) * DINNER];
                nu[q] = bf2f(up[(size_t)(lo + 4 + q) * DINNER]);
            }
        }
        #pragma unroll
        for (int q = 0; q < 4; q++) {
            const float dvq = dv[q];
            const float du  = dvq * uv[q];
            sd += dvq;
            const f32x4* Bv = (const f32x4*)&Bs[(lo + q) * DSTATE];
            #pragma unroll
            for (int s4 = 0; s4 < 4; s4++) {
                f32x4 bb = Bv[s4];
                #pragma unroll
                for (int k = 0; k < 4; k++) {
                    int s = s4 * 4 + k;
                    Er[s] = __expf(dvq * A[s]) * Er[s] + du * bb[k];
                }
            }
        }
        #pragma unroll
        for (int q = 0; q < 4; q++) { dv[q] = nd[q]; uv[q] = nu[q]; }
    }

    const long long o = ((long long)((b * NCH + c) * DINNER) + d) * DSTATE;
    #pragma unroll
    for (int s = 0; s < DSTATE; s++) {
        P[o + s] = __expf(A[s] * sd);
        E[o + s] = Er[s];
    }
}

__global__ __launch_bounds__(256) void scan_pass2(
    const float* __restrict__ P, float* __restrict__ E)
{
    const int gid  = blockIdx.x * 256 + threadIdx.x;
    const int b    = gid >> 15;
    const int rest = gid & 32767;
    float h = 0.0f;
    for (int c = 0; c < NCH; c++) {
        const long long idx = (long long)(b * NCH + c) * (DINNER * DSTATE) + rest;
        float p = P[idx];
        float e = E[idx];
        E[idx] = h;
        h = p * h + e;
    }
}

// pass3: emit y in bf16, fused silu(z) gate (z from bf16 xz cols 2048..4096).
__global__ __launch_bounds__(256) void scan_pass3(
    const unsigned short* __restrict__ xc16, const float* __restrict__ delta,
    const float* __restrict__ dbc, const float* __restrict__ A_log,
    const float* __restrict__ D_skip, const float* __restrict__ Hin,
    const unsigned short* __restrict__ xz16, unsigned short* __restrict__ y16)
{
    __shared__ float BCs[CS * 2 * DSTATE];
    const int tid = threadIdx.x;
    const int db  = blockIdx.x & 7;
    const int c   = (blockIdx.x >> 3) & (NCH - 1);
    const int b   = blockIdx.x >> 9;
    const int d   = db * 256 + tid;
    const int t0  = b * L_SZ + c * CS;

    for (int idx = tid; idx < CS * 2 * DSTATE; idx += 256) {
        int step = idx >> 5, i = idx & 31;
        BCs[idx] = dbc[(t0 + step) * 96 + DTRANK + i];
    }

    float A[DSTATE], h[DSTATE];
    const long long o = ((long long)((b * NCH + c) * DINNER) + d) * DSTATE;
    #pragma unroll
    for (int s = 0; s < DSTATE; s++) {
        A[s] = -__expf(A_log[d * DSTATE + s]);
        h[s] = Hin[o + s];
    }
    const float Dv = D_skip[d];

    const float* dp = delta + (size_t)t0 * DINNER + d;
    const unsigned short* up = xc16 + (size_t)t0 * DINNER + d;
    const unsigned short* zp = xz16 + (size_t)t0 * 4096 + DINNER + d;
    unsigned short* yp = y16 + (size_t)t0 * DINNER + d;

    float dv[4], uv[4], zv[4];
    #pragma unroll
    for (int q = 0; q < 4; q++) {
        dv[q] = dp[(size_t)q * DINNER];
        uv[q] = bf2f(up[(size_t)q * DINNER]);
        zv[q] = bf2f(zp[(size_t)q * 4096]);
    }
    __syncthreads();

    for (int lo = 0; lo < CS; lo += 4) {
        float nd[4], nu[4], nz[4];
        if (lo + 4 < CS) {
            #pragma unroll
            for (int q = 0; q < 4; q++) {
                nd[q] = dp[(size_t)(lo + 4 + q) * DINNER];
                nu[q] = bf2f(up[(size_t)(lo + 4 + q) * DINNER]);
                nz[q] = bf2f(zp[(size_t)(lo + 4 + q) * 4096]);
            }
        }
        #pragma unroll
        for (int q = 0; q < 4; q++) {
            const float dvq = dv[q];
            const float uvq = uv[q];
            const float du  = dvq * uvq;
            const f32x4* Bv = (const f32x4*)&BCs[(lo + q) * 32];
            float yv = 0.0f;
            #pragma unroll
            for (int s4 = 0; s4 < 4; s4++) {
                f32x4 bb = Bv[s4];
                f32x4 cc = Bv[4 + s4];
                #pragma unroll
                for (int k = 0; k < 4; k++) {
                    int s = s4 * 4 + k;
                    float dA = __expf(dvq * A[s]);
                    h[s] = dA * h[s] + du * bb[k];
                    yv  += h[s] * cc[k];
                }
            }
            yp[(size_t)(lo + q) * DINNER] = f2bf((uvq * Dv + yv) * silu_f(zv[q]));
        }
        #pragma unroll
        for (int q = 0; q < 4; q++) { dv[q] = nd[q]; uv[q] = nu[q]; zv[q] = nz[q]; }
    }
}

extern "C" void kernel_launch(void* const* d_in, const int* in_sizes, int n_in,
                              void* d_out, int out_size, void* d_ws, size_t ws_size,
                              hipStream_t stream) {
    const float* x       = (const float*)d_in[0];
    const float* W_in    = (const float*)d_in[1];
    const float* conv_w  = (const float*)d_in[2];
    const float* conv_b  = (const float*)d_in[3];
    const float* W_xproj = (const float*)d_in[4];
    const float* W_dt    = (const float*)d_in[5];
    const float* b_dt    = (const float*)d_in[6];
    const float* A_log   = (const float*)d_in[7];
    const float* D_skip  = (const float*)d_in[8];
    const float* W_out   = (const float*)d_in[9];
    float* out = (float*)d_out;

    // workspace layout, float units (141 MB). Aliases (dead-before-reuse):
    //   parts (dead after reduce) shares Pbuf (written at pass1)
    //   x16 (dead after gemm1)    shares yb16 (written at pass3)
    //   parts6 (GEMM6 split-K partials, 64MB) spans delta..Pbuf — all dead
    //   after pass3; GEMM6/reduce4 run after pass3. 16777216 f exactly. ✓
    float* ws = (float*)d_ws;
    unsigned short* xz16   = (unsigned short*)ws;              // [0 .. 8388608) f
    unsigned short* xc16   = (unsigned short*)(ws +  8388608); // [.. 12582912) f
    float* dbc             = ws + 12582912;                    // [.. 12976128) f
    unsigned short* dtlo16 = (unsigned short*)(ws + 12976128); // [.. 13107200) f
    float* delta           = ws + 13107200;                    // [.. 21495808) f
    float* Ebuf            = ws + 21495808;                    // [.. 25690112) f : 2*64*2048*16
    float* Pbuf            = ws + 25690112;                    // [.. 29884416) f : 2*64*2048*16
    float* parts           = Pbuf;                             //   alias, 3145728 f < 4194304 ✓
    float* parts6          = delta;                            //   alias, 4*4096*1024 = 16777216 f ✓
    unsigned short* yb16   = (unsigned short*)(ws + 29884416); // [.. 31981568) f
    unsigned short* x16    = yb16;                             //   alias
    unsigned short* W_inT    = (unsigned short*)(ws + 31981568); // [.. 34078720) f
    unsigned short* W_xprojT = (unsigned short*)(ws + 34078720); // [.. 34177024) f
    unsigned short* W_dtT    = (unsigned short*)(ws + 34177024); // [.. 34242560) f
    unsigned short* W_outT   = (unsigned short*)(ws + 34242560); // [.. 35291136) f

    const int MT = 4096;  // B*L tokens

    transpose_cast<<<dim3(128, 32), 256, 0, stream>>>(W_in,    W_inT,    1024, 4096);
    transpose_cast<<<dim3(  3, 64), 256, 0, stream>>>(W_xproj, W_xprojT, 2048,   96);
    transpose_cast<<<dim3( 64,  2), 256, 0, stream>>>(W_dt,    W_dtT,      64, 2048);
    transpose_cast<<<dim3( 32, 64), 256, 0, stream>>>(W_out,   W_outT,   2048, 1024);
    cast_bf16<<<dim3(2048), 256, 0, stream>>>(x, x16, 524288);

    // 1) xz = x @ W_in              (4096 x 4096, K=1024) -> bf16, 8-phase
    gemm_8ph<1><<<dim3(256), 512, 0, stream>>>(
        x16, W_inT, xz16, MT, 4096, 1024, 1024, 4096, 1024);

    // 2) xc16 = silu(causal_dwconv(xin) + b)
    conv_silu_v2<<<dim3(8, 64, 2), 256, 0, stream>>>(xz16, conv_w, conv_b, xc16);

    // 3) dbc = xc @ W_xproj         (4096 x 96, K=2048) — split-K x8
    gemm_bt_lds<0, 0><<<dim3(1, 32, 8), 256, 0, stream>>>(
        xc16, W_xprojT, parts, nullptr, MT, 96, 2048, 2048, 2048, 96, 256);
    reduce_splitk<<<dim3(1536), 256, 0, stream>>>(parts, dbc, dtlo16, MT * 96, 8);

    // 4) delta = softplus(dt_lo @ W_dt + b_dt)  (4096 x 2048, K=64) — fast softplus
    gemm_bt_lds<1, 0><<<dim3(16, 32), 256, 0, stream>>>(
        dtlo16, W_dtT, delta, b_dt, MT, 2048, 64, 64, 64, 2048, 64);

    // 5) chunked selective scan + fused gate (bf16 y out)
    scan_pass1<<<dim3(1024), 256, 0, stream>>>(xc16, delta, dbc, A_log, Pbuf, Ebuf);
    scan_pass2<<<dim3(256), 256, 0, stream>>>(Pbuf, Ebuf);
    scan_pass3<<<dim3(1024), 256, 0, stream>>>(xc16, delta, dbc, A_log, D_skip,
                                               Ebuf, xz16, yb16);

    // 6) out = y @ W_out   (4096 x 1024, K=2048) — 8-phase, split-K x4
    //    NOTE: ldb = 2048 (W_outT row stride = K). Round-2 bug was ldb=1024.
    gemm_8ph<0><<<dim3(64, 1, 4), 512, 0, stream>>>(
        yb16, W_outT, parts6, MT, 1024, 2048, 2048, 1024, 512);
    reduce4<<<dim3(4096), 256, 0, stream>>>(parts6, out, MT * 1024 / 4);
}

// Round 4
// 310.663 us; speedup vs baseline: 1.0522x; 1.0006x over previous
//
#include <hip/hip_runtime.h>
#include <math.h>

#define B_SZ 2
#define L_SZ 2048
#define DMODEL 1024
#define DINNER 2048
#define DSTATE 16
#define DCONV 4
#define DTRANK 64

#define CS 32                    // scan chunk size
#define NCH (L_SZ / CS)          // 64 chunks per batch

typedef float f32x4 __attribute__((ext_vector_type(4)));
typedef __bf16 bf16x8 __attribute__((ext_vector_type(8)));

__device__ __forceinline__ float silu_f(float x) {
    return x / (1.0f + __expf(-x));
}

// fast softplus: max(x,0) + log(1+exp(-|x|)); abs err ~1e-6, branch-free tails
__device__ __forceinline__ float softplus_f(float x) {
    return fmaxf(x, 0.0f) + __logf(1.0f + __expf(-fabsf(x)));
}

// fp32 -> bf16 round-to-nearest-even on raw bits
__device__ __forceinline__ unsigned short f2bf(float x) {
    unsigned int u = __float_as_uint(x);
    u = u + 0x7FFFu + ((u >> 16) & 1u);
    return (unsigned short)(u >> 16);
}

__device__ __forceinline__ float bf2f(unsigned short s) {
    return __uint_as_float(((unsigned int)s) << 16);
}

// async global->LDS DMA, 16B per lane; deposits at base + lane*16B.
__device__ __forceinline__ void gload_lds16(const unsigned short* g, unsigned short* l) {
    __builtin_amdgcn_global_load_lds(
        (const __attribute__((address_space(1))) void*)g,
        (__attribute__((address_space(3))) void*)l, 16, 0, 0);
}

union Pack8 { unsigned short s[8]; uint4 v; };

// Transpose + cast: W[R,C] fp32 -> WT[C,R] bf16. Grid (C/32, R/32), 256 thr.
__global__ __launch_bounds__(256) void transpose_cast(
    const float* __restrict__ W, unsigned short* __restrict__ WT, int R, int C)
{
    __shared__ float t[32][33];
    const int tx = threadIdx.x & 31;
    const int ty = threadIdx.x >> 5;
    const int r0 = blockIdx.y * 32;
    const int c0 = blockIdx.x * 32;
    #pragma unroll
    for (int i = 0; i < 4; i++)
        t[ty + i * 8][tx] = W[(r0 + ty + i * 8) * C + c0 + tx];
    __syncthreads();
    #pragma unroll
    for (int i = 0; i < 4; i++)
        WT[(c0 + ty + i * 8) * R + r0 + tx] = f2bf(t[tx][ty + i * 8]);
}

// cast fp32 -> bf16, 8 elems/thread
__global__ __launch_bounds__(256) void cast_bf16(
    const float* __restrict__ src, unsigned short* __restrict__ dst, int n8)
{
    int i = blockIdx.x * 256 + threadIdx.x;
    if (i >= n8) return;
    const float4 f0 = *(const float4*)(src + i * 8);
    const float4 f1 = *(const float4*)(src + i * 8 + 4);
    Pack8 p;
    p.s[0] = f2bf(f0.x); p.s[1] = f2bf(f0.y); p.s[2] = f2bf(f0.z); p.s[3] = f2bf(f0.w);
    p.s[4] = f2bf(f1.x); p.s[5] = f2bf(f1.y); p.s[6] = f2bf(f1.z); p.s[7] = f2bf(f1.w);
    *(uint4*)(dst + i * 8) = p.v;
}

// ---- bf16 MFMA GEMM, B pre-transposed, global_load_lds staging -------------
// (128x128 2-phase kernel, kept for the small GEMMs 3 and 4.)
template <int ACT, int OBF16>
__global__ __launch_bounds__(256) void gemm_bt_lds(
    const unsigned short* __restrict__ A, const unsigned short* __restrict__ BT,
    void* __restrict__ Cout, const float* __restrict__ bias,
    int M, int N, int K, int lda, int ldb, int ldc, int Kc)
{
    __shared__ unsigned short As[128 * 64];
    __shared__ unsigned short Bs[128 * 64];

    const int tid  = threadIdx.x;
    const int lane = tid & 63;
    const int wave = tid >> 6;
    const int wm   = wave >> 1;
    const int wn   = wave & 1;
    const int row0 = blockIdx.y * 128;
    const int col0 = blockIdx.x * 128;
    const int lq   = lane >> 4;
    const int lm   = lane & 15;
    const int kbeg = blockIdx.z * Kc;

    const int rloc = wave * 32 + (lane >> 3);
    const int sc   = (lane & 7) ^ ((lane >> 3) & 7);
    const unsigned short* gA = A + (size_t)(row0 + rloc) * lda + sc * 8;
    const unsigned short* gBp[4];
    #pragma unroll
    for (int is = 0; is < 4; is++) {
        int br = col0 + rloc + 8 * is;
        if (br > N - 1) br = N - 1;
        gBp[is] = BT + (size_t)br * ldb + sc * 8;
    }
    unsigned short* lA = As + wave * 2048;
    unsigned short* lB = Bs + wave * 2048;

    f32x4 acc[4][4];
    #pragma unroll
    for (int i = 0; i < 4; i++)
        #pragma unroll
        for (int j = 0; j < 4; j++)
            #pragma unroll
            for (int r = 0; r < 4; r++) acc[i][j][r] = 0.0f;

    for (int k0 = kbeg; k0 < kbeg + Kc; k0 += 64) {
        #pragma unroll
        for (int is = 0; is < 4; is++) {
            gload_lds16(gA + (size_t)(8 * is) * lda + k0, lA + is * 512);
            gload_lds16(gBp[is] + k0, lB + is * 512);
        }
        __syncthreads();

        #pragma unroll
        for (int ks = 0; ks < 2; ks++) {
            bf16x8 af[4], bfr[4];
            #pragma unroll
            for (int i = 0; i < 4; i++) {
                int row = wm * 64 + i * 16 + lm;
                af[i] = *(const bf16x8*)&As[row * 64 + (((ks * 4 + lq) ^ (row & 7)) * 8)];
            }
            #pragma unroll
            for (int j = 0; j < 4; j++) {
                int row = wn * 64 + j * 16 + lm;
                bfr[j] = *(const bf16x8*)&Bs[row * 64 + (((ks * 4 + lq) ^ (row & 7)) * 8)];
            }
            #pragma unroll
            for (int i = 0; i < 4; i++)
                #pragma unroll
                for (int j = 0; j < 4; j++)
                    acc[i][j] = __builtin_amdgcn_mfma_f32_16x16x32_bf16(
                        af[i], bfr[j], acc[i][j], 0, 0, 0);
        }
        __syncthreads();
    }

    // epilogue: C/D layout col=lane&15, row=(lane>>4)*4+reg
    #pragma unroll
    for (int i = 0; i < 4; i++) {
        #pragma unroll
        for (int r = 0; r < 4; r++) {
            int row = row0 + wm * 64 + i * 16 + lq * 4 + r;
            #pragma unroll
            for (int j = 0; j < 4; j++) {
                int col = col0 + wn * 64 + j * 16 + lm;
                if (col < N) {
                    float v = acc[i][j][r];
                    if (ACT == 1) v = softplus_f(v + bias[col]);
                    if (OBF16) {
                        unsigned short* Cz = (unsigned short*)Cout +
                            (size_t)blockIdx.z * (size_t)M * ldc;
                        Cz[(size_t)row * ldc + col] = f2bf(v);
                    } else {
                        float* Cz = (float*)Cout +
                            (size_t)blockIdx.z * (size_t)M * ldc;
                        Cz[(size_t)row * ldc + col] = v;
                    }
                }
            }
        }
    }
}

// ---- 256x256 8-phase bf16 GEMM (m201-style), counted vmcnt + setprio -------
// 512 thr = 8 waves (2M x 4N), per-wave 128x64 out, BK=64, NT = Kc/64 K-tiles.
// LDS 128KB: sm[buf][A|B][unit:4][64x64 bf16]. Unit u = 64 rows (A: tile rows
// u*64.., B: tile cols u*64..). XOR-swizzle: LDS[r][g] = global[r][g^(r&7)],
// staged linearly via pre-swizzled source (both-sides-or-neither, rule #21).
//
// Per K-tile: 4 phases; phase q computes i-pair (2q,2q+1) x 4j x both ks
// (16 MFMA). B units are dead after ph0; A units after ph1/ph3 ->
// staging calendar (per tile t, 2 units/phase):
//   q0: (t+1).a1,a3   q1: (t+1).b2,b3   [other buffer, always safe]
//   q2: (t+2).b0,b1   q3: (t+2).a0,a2   [this buffer, regions dead]
// One vmcnt(4) per K-tile retires exactly tile t's 8 units (vmcnt(0) only at
// t=NT-1). Units are staged 5-6 phases ahead.
template <int OBF16>
__global__ __launch_bounds__(512, 2) void gemm_8ph(
    const unsigned short* __restrict__ A, const unsigned short* __restrict__ BT,
    void* __restrict__ Cout, int M, int N, int lda, int ldb, int ldc, int Kc)
{
    __shared__ unsigned short sm[2][2][4][64 * 64];

    const int tid  = threadIdx.x;
    const int lane = tid & 63;
    const int wave = tid >> 6;         // 0..7
    const int wm   = wave >> 2;        // 0..1  (128-row half)
    const int wn   = wave & 3;         // 0..3  (64-col quarter)
    const int lq   = lane >> 4;
    const int lm   = lane & 15;

    // bijective XCD swizzle (gridDim.x % 8 == 0 guaranteed by caller)
    const int cpx = gridDim.x >> 3;
    const int ti  = (blockIdx.x & 7) * cpx + (blockIdx.x >> 3);
    const int nbx = N >> 8;
    const int row0 = (ti / nbx) * 256;
    const int col0 = (ti % nbx) * 256;
    const int kbeg = blockIdx.z * Kc;

    // staging: one gload per thread per 64-row unit (512 thr x 16B = 8KB)
    const int r  = tid >> 3;                 // row within unit, 0..63
    const int sc = (tid & 7) ^ (r & 7);      // pre-swizzled source group
    const unsigned short* gA = A + (size_t)(row0 + r) * lda + sc * 8 + kbeg;
    const unsigned short* gB[4];
    #pragma unroll
    for (int u = 0; u < 4; u++) {
        int br = col0 + u * 64 + r;
        if (br > N - 1) br = N - 1;
        gB[u] = BT + (size_t)br * ldb + sc * 8 + kbeg;
    }

    #define STA(bsel, u, kk) gload_lds16(gA + (size_t)((u) * 64) * lda + (kk), \
                                         &sm[bsel][0][u][wave * 512])
    #define STB(bsel, u, kk) gload_lds16(gB[u] + (kk), &sm[bsel][1][u][wave * 512])

    f32x4 acc[8][4];
    #pragma unroll
    for (int i = 0; i < 8; i++)
        #pragma unroll
        for (int j = 0; j < 4; j++)
            #pragma unroll
            for (int rr = 0; rr < 4; rr++) acc[i][j][rr] = 0.0f;

    const int NT = Kc >> 6;
    // prologue, exact issue order (oldest->newest) matched to vmcnt(4) math:
    // [0.b0 0.b1][0.a0 0.a2][0.a1 0.a3][0.b2 0.b3][1.b0 1.b1][1.a0 1.a2]
    STB(0, 0, 0); STB(0, 1, 0); STA(0, 0, 0); STA(0, 2, 0);
    STA(0, 1, 0); STA(0, 3, 0); STB(0, 2, 0); STB(0, 3, 0);
    if (NT > 1) { STB(1, 0, 64); STB(1, 1, 64); STA(1, 0, 64); STA(1, 2, 64); }

    bf16x8 bq[4][2];

    for (int t = 0; t < NT; ++t) {
        const int b   = t & 1;
        const int kk1 = (t + 1) * 64;
        const int kk2 = (t + 2) * 64;

        if (t == NT - 1) asm volatile("s_waitcnt vmcnt(0)" ::: "memory");
        else             asm volatile("s_waitcnt vmcnt(4)" ::: "memory");
        __builtin_amdgcn_s_barrier();
        __builtin_amdgcn_sched_barrier(0);

        #pragma unroll
        for (int q = 0; q < 4; ++q) {
            bf16x8 af2[2][2];
            #pragma unroll
            for (int ii = 0; ii < 2; ii++) {
                int br = wm * 128 + (2 * q + ii) * 16 + lm;
                #pragma unroll
                for (int ks = 0; ks < 2; ks++)
                    af2[ii][ks] = *(const bf16x8*)&sm[b][0][br >> 6]
                        [(br & 63) * 64 + (((ks * 4 + lq) ^ (br & 7)) * 8)];
            }
            if (q == 0) {
                #pragma unroll
                for (int j = 0; j < 4; j++) {
                    int br = wn * 64 + j * 16 + lm;
                    #pragma unroll
                    for (int ks = 0; ks < 2; ks++)
                        bq[j][ks] = *(const bf16x8*)&sm[b][1][br >> 6]
                            [(br & 63) * 64 + (((ks * 4 + lq) ^ (br & 7)) * 8)];
                }
            }
            // staging calendar (2 units / phase)
            if (q == 0 && t + 1 < NT) { STA(b ^ 1, 1, kk1); STA(b ^ 1, 3, kk1); }
            if (q == 1 && t + 1 < NT) { STB(b ^ 1, 2, kk1); STB(b ^ 1, 3, kk1); }
            if (q == 2 && t + 2 < NT) { STB(b, 0, kk2); STB(b, 1, kk2); }
            if (q == 3 && t + 2 < NT) { STA(b, 0, kk2); STA(b, 2, kk2); }

            asm volatile("s_waitcnt lgkmcnt(0)" ::: "memory");
            __builtin_amdgcn_sched_barrier(0);
            __builtin_amdgcn_s_setprio(1);
            #pragma unroll
            for (int ii = 0; ii < 2; ii++)
                #pragma unroll
                for (int j = 0; j < 4; j++) {
                    acc[2 * q + ii][j] = __builtin_amdgcn_mfma_f32_16x16x32_bf16(
                        af2[ii][0], bq[j][0], acc[2 * q + ii][j], 0, 0, 0);
                    acc[2 * q + ii][j] = __builtin_amdgcn_mfma_f32_16x16x32_bf16(
                        af2[ii][1], bq[j][1], acc[2 * q + ii][j], 0, 0, 0);
                }
            __builtin_amdgcn_s_setprio(0);
            __builtin_amdgcn_sched_barrier(0);
            if (q < 3) {
                __builtin_amdgcn_s_barrier();
                __builtin_amdgcn_sched_barrier(0);
            }
        }
    }
    #undef STA
    #undef STB

    // epilogue: C/D layout col=lane&15, row=(lane>>4)*4+reg
    const size_t zoff = (size_t)blockIdx.z * (size_t)M * ldc;
    #pragma unroll
    for (int i = 0; i < 8; i++) {
        #pragma unroll
        for (int rr = 0; rr < 4; rr++) {
            int row = row0 + wm * 128 + i * 16 + lq * 4 + rr;
            #pragma unroll
            for (int j = 0; j < 4; j++) {
                int col = col0 + wn * 64 + j * 16 + lm;
                if (col < N) {
                    float v = acc[i][j][rr];
                    if (OBF16)
                        ((unsigned short*)Cout)[(size_t)row * ldc + col] = f2bf(v);
                    else
                        ((float*)Cout)[zoff + (size_t)row * ldc + col] = v;
                }
            }
        }
    }
}

// Sum nsplit partial C buffers; also emit bf16 copy of cols<64 (dt_lo).
__global__ __launch_bounds__(256) void reduce_splitk(
    const float* __restrict__ part, float* __restrict__ C,
    unsigned short* __restrict__ dtlo16, int n, int nsplit)
{
    int i = blockIdx.x * 256 + threadIdx.x;
    if (i >= n) return;
    float s = 0.0f;
    for (int z = 0; z < nsplit; z++) s += part[(size_t)z * n + i];
    C[i] = s;
    int row = i / 96;
    int col = i - row * 96;
    if (col < DTRANK) dtlo16[row * DTRANK + col] = f2bf(s);
}

// Sum 4 fp32 partials, vectorized. n4 = total_floats/4.
__global__ __launch_bounds__(256) void reduce4(
    const float* __restrict__ part, float* __restrict__ out, int n4)
{
    int i = blockIdx.x * 256 + threadIdx.x;
    if (i >= n4) return;
    const f32x4* p = (const f32x4*)part;
    f32x4 s = p[i];
    s += p[i + n4];
    s += p[i + 2 * n4];
    s += p[i + 3 * n4];
    ((f32x4*)out)[i] = s;
}

// conv + silu, register-rolling window along l. Reads bf16 xz (cols 0..2048),
// emits bf16 xc16. grid (8, 64, 2).
__global__ __launch_bounds__(256) void conv_silu_v2(
    const unsigned short* __restrict__ xz16, const float* __restrict__ conv_w,
    const float* __restrict__ conv_b, unsigned short* __restrict__ xc16)
{
    const int tid = threadIdx.x;
    const int d   = blockIdx.x * 256 + tid;
    const int l0  = blockIdx.y * 32;
    const int b   = blockIdx.z;
    const float4 w  = *(const float4*)(conv_w + d * 4);
    const float bias = conv_b[d];
    const int t0 = b * L_SZ + l0;
    const unsigned short* src = xz16 + (size_t)t0 * 4096 + d;

    float r0, r1, r2;
    if (l0 == 0) {
        r0 = r1 = r2 = 0.0f;
    } else {
        r0 = bf2f(src[-3 * 4096]);
        r1 = bf2f(src[-2 * 4096]);
        r2 = bf2f(src[-1 * 4096]);
    }
    #pragma unroll 4
    for (int l = 0; l < 32; l++) {
        float r3 = bf2f(src[(size_t)l * 4096]);
        float acc = bias + r0 * w.x + r1 * w.y + r2 * w.z + r3 * w.w;
        xc16[(size_t)(t0 + l) * DINNER + d] = f2bf(silu_f(acc));
        r0 = r1; r1 = r2; r2 = r3;
    }
}

// ---- Chunked parallel selective scan (CS=32) --------------------------------
// v3: 2-way STATE SPLIT. Thread pair (2i, 2i+1) shares channel d; sh=tid&1
// selects states [sh*8, sh*8+8). Halves per-thread exp/fma chain, doubles
// wave count (grid 2048 blocks = 8/CU -> full occupancy). Pair lanes read the
// same delta/xc/z address (HW broadcast); P/E writes are 32B/lane contiguous.
// grid: B * NCH * 16 = 2048; db=blk&15, c=(blk>>4)&63, b=blk>>10.
__global__ __launch_bounds__(256) void scan_pass1(
    const unsigned short* __restrict__ xc16, const float* __restrict__ delta,
    const float* __restrict__ dbc, const float* __restrict__ A_log,
    float* __restrict__ P, float* __restrict__ E)
{
    __shared__ float Bs[CS * DSTATE];
    const int tid = threadIdx.x;
    const int db  = blockIdx.x & 15;
    const int c   = (blockIdx.x >> 4) & (NCH - 1);
    const int b   = blockIdx.x >> 10;
    const int dl  = tid >> 1;          // channel within block, 0..127
    const int sh  = tid & 1;           // state half
    const int d   = db * 128 + dl;
    const int t0  = b * L_SZ + c * CS;

    for (int idx = tid; idx < CS * DSTATE; idx += 256) {
        int step = idx >> 4, i = idx & 15;
        Bs[idx] = dbc[(t0 + step) * 96 + DTRANK + i];
    }

    float A[8], Er[8];
    const float* Ap = A_log + d * DSTATE + sh * 8;
    #pragma unroll
    for (int k = 0; k < 8; k++) {
        A[k]  = -__expf(Ap[k]);
        Er[k] = 0.0f;
    }
    float sd = 0.0f;

    const float* dp = delta + (size_t)t0 * DINNER + d;
    const unsigned short* up = xc16 + (size_t)t0 * DINNER + d;

    float dv[4], uv[4];
    #pragma unroll
    for (int q = 0; q < 4; q++) {
        dv[q] = dp[(size_t)q * DINNER];
        uv[q] = bf2f(up[(size_t)q * DINNER]);
    }
    __syncthreads();

    for (int lo = 0; lo < CS; lo += 4) {
        float nd[4], nu[4];
        if (lo + 4 < CS) {
            #pragma unroll
            for (int q = 0; q < 4; q++) {
                nd[q] = dp[(size_t)(lo + 4 + q) * DINNER];
                nu[q] = bf2f(up[(size_t)(lo + 4 + q) * DINNER]);
            }
        }
        #pragma unroll
        for (int q = 0; q < 4; q++) {
            const float dvq = dv[q];
            const float du  = dvq * uv[q];
            sd += dvq;
            const f32x4* Bv = (const f32x4*)&Bs[(lo + q) * DSTATE + sh * 8];
            #pragma unroll
            for (int s4 = 0; s4 < 2; s4++) {
                f32x4 bb = Bv[s4];
                #pragma unroll
                for (int k = 0; k < 4; k++) {
                    int s = s4 * 4 + k;
                    Er[s] = __expf(dvq * A[s]) * Er[s] + du * bb[k];
                }
            }
        }
        #pragma unroll
        for (int q = 0; q < 4; q++) { dv[q] = nd[q]; uv[q] = nu[q]; }
    }

    const long long o = ((long long)((b * NCH + c) * DINNER) + d) * DSTATE + sh * 8;
    f32x4 pv0, pv1, ev0, ev1;
    #pragma unroll
    for (int k = 0; k < 4; k++) {
        pv0[k] = __expf(A[k] * sd);
        pv1[k] = __expf(A[4 + k] * sd);
        ev0[k] = Er[k];
        ev1[k] = Er[4 + k];
    }
    *(f32x4*)(P + o)     = pv0;
    *(f32x4*)(P + o + 4) = pv1;
    *(f32x4*)(E + o)     = ev0;
    *(f32x4*)(E + o + 4) = ev1;
}

__global__ __launch_bounds__(256) void scan_pass2(
    const float* __restrict__ P, float* __restrict__ E)
{
    const int gid  = blockIdx.x * 256 + threadIdx.x;
    const int b    = gid >> 15;
    const int rest = gid & 32767;
    float h = 0.0f;
    for (int c = 0; c < NCH; c++) {
        const long long idx = (long long)(b * NCH + c) * (DINNER * DSTATE) + rest;
        float p = P[idx];
        float e = E[idx];
        E[idx] = h;
        h = p * h + e;
    }
}

// pass3 v3: 2-way state split (see pass1). yv halves combined via
// __shfl_xor(1); even lane (sh=0) writes y16 (dense 2B stream across pairs).
__global__ __launch_bounds__(256) void scan_pass3(
    const unsigned short* __restrict__ xc16, const float* __restrict__ delta,
    const float* __restrict__ dbc, const float* __restrict__ A_log,
    const float* __restrict__ D_skip, const float* __restrict__ Hin,
    const unsigned short* __restrict__ xz16, unsigned short* __restrict__ y16)
{
    __shared__ float BCs[CS * 2 * DSTATE];
    const int tid = threadIdx.x;
    const int db  = blockIdx.x & 15;
    const int c   = (blockIdx.x >> 4) & (NCH - 1);
    const int b   = blockIdx.x >> 10;
    const int dl  = tid >> 1;
    const int sh  = tid & 1;
    const int d   = db * 128 + dl;
    const int t0  = b * L_SZ + c * CS;

    for (int idx = tid; idx < CS * 2 * DSTATE; idx += 256) {
        int step = idx >> 5, i = idx & 31;
        BCs[idx] = dbc[(t0 + step) * 96 + DTRANK + i];
    }

    float A[8], h[8];
    const float* Ap = A_log + d * DSTATE + sh * 8;
    const long long o = ((long long)((b * NCH + c) * DINNER) + d) * DSTATE + sh * 8;
    #pragma unroll
    for (int k = 0; k < 8; k++) {
        A[k] = -__expf(Ap[k]);
        h[k] = Hin[o + k];
    }
    const float Dv = D_skip[d];

    const float* dp = delta + (size_t)t0 * DINNER + d;
    const unsigned short* up = xc16 + (size_t)t0 * DINNER + d;
    const unsigned short* zp = xz16 + (size_t)t0 * 4096 + DINNER + d;
    unsigned short* yp = y16 + (size_t)t0 * DINNER + d;

    float dv[4], uv[4], zv[4];
    #pragma unroll
    for (int q = 0; q < 4; q++) {
        dv[q] = dp[(size_t)q * DINNER];
        uv[q] = bf2f(up[(size_t)q * DINNER]);
        zv[q] = bf2f(zp[(size_t)q * 4096]);
    }
    __syncthreads();

    for (int lo = 0; lo < CS; lo += 4) {
        float nd[4], nu[4], nz[4];
        if (lo + 4 < CS) {
            #pragma unroll
            for (int q = 0; q < 4; q++) {
                nd[q] = dp[(size_t)(lo + 4 + q) * DINNER];
                nu[q] = bf2f(up[(size_t)(lo + 4 + q) * DINNER]);
                nz[q] = bf2f(zp[(size_t)(lo + 4 + q) * 4096]);
            }
        }
        #pragma unroll
        for (int q = 0; q < 4; q++) {
            const float dvq = dv[q];
            const float uvq = uv[q];
            const float du  = dvq * uvq;
            const f32x4* Bv = (const f32x4*)&BCs[(lo + q) * 32 + sh * 8];
            const f32x4* Cv = (const f32x4*)&BCs[(lo + q) * 32 + DSTATE + sh * 8];
            float yv = 0.0f;
            #pragma unroll
            for (int s4 = 0; s4 < 2; s4++) {
                f32x4 bb = Bv[s4];
                f32x4 cc = Cv[s4];
                #pragma unroll
                for (int k = 0; k < 4; k++) {
                    int s = s4 * 4 + k;
                    float dA = __expf(dvq * A[s]);
                    h[s] = dA * h[s] + du * bb[k];
                    yv  += h[s] * cc[k];
                }
            }
            yv += __shfl_xor(yv, 1);
            if (sh == 0)
                yp[(size_t)(lo + q) * DINNER] = f2bf((uvq * Dv + yv) * silu_f(zv[q]));
        }
        #pragma unroll
        for (int q = 0; q < 4; q++) { dv[q] = nd[q]; uv[q] = nu[q]; zv[q] = nz[q]; }
    }
}

extern "C" void kernel_launch(void* const* d_in, const int* in_sizes, int n_in,
                              void* d_out, int out_size, void* d_ws, size_t ws_size,
                              hipStream_t stream) {
    const float* x       = (const float*)d_in[0];
    const float* W_in    = (const float*)d_in[1];
    const float* conv_w  = (const float*)d_in[2];
    const float* conv_b  = (const float*)d_in[3];
    const float* W_xproj = (const float*)d_in[4];
    const float* W_dt    = (const float*)d_in[5];
    const float* b_dt    = (const float*)d_in[6];
    const float* A_log   = (const float*)d_in[7];
    const float* D_skip  = (const float*)d_in[8];
    const float* W_out   = (const float*)d_in[9];
    float* out = (float*)d_out;

    // workspace layout, float units (141 MB). Aliases (dead-before-reuse):
    //   parts (dead after reduce) shares Pbuf (written at pass1)
    //   x16 (dead after gemm1)    shares yb16 (written at pass3)
    //   parts6 (GEMM6 split-K partials, 64MB) spans delta..Pbuf — all dead
    //   after pass3; GEMM6/reduce4 run after pass3. 16777216 f exactly. ✓
    float* ws = (float*)d_ws;
    unsigned short* xz16   = (unsigned short*)ws;              // [0 .. 8388608) f
    unsigned short* xc16   = (unsigned short*)(ws +  8388608); // [.. 12582912) f
    float* dbc             = ws + 12582912;                    // [.. 12976128) f
    unsigned short* dtlo16 = (unsigned short*)(ws + 12976128); // [.. 13107200) f
    float* delta           = ws + 13107200;                    // [.. 21495808) f
    float* Ebuf            = ws + 21495808;                    // [.. 25690112) f : 2*64*2048*16
    float* Pbuf            = ws + 25690112;                    // [.. 29884416) f : 2*64*2048*16
    float* parts           = Pbuf;                             //   alias, 3145728 f < 4194304 ✓
    float* parts6          = delta;                            //   alias, 4*4096*1024 = 16777216 f ✓
    unsigned short* yb16   = (unsigned short*)(ws + 29884416); // [.. 31981568) f
    unsigned short* x16    = yb16;                             //   alias
    unsigned short* W_inT    = (unsigned short*)(ws + 31981568); // [.. 34078720) f
    unsigned short* W_xprojT = (unsigned short*)(ws + 34078720); // [.. 34177024) f
    unsigned short* W_dtT    = (unsigned short*)(ws + 34177024); // [.. 34242560) f
    unsigned short* W_outT   = (unsigned short*)(ws + 34242560); // [.. 35291136) f

    const int MT = 4096;  // B*L tokens

    transpose_cast<<<dim3(128, 32), 256, 0, stream>>>(W_in,    W_inT,    1024, 4096);
    transpose_cast<<<dim3(  3, 64), 256, 0, stream>>>(W_xproj, W_xprojT, 2048,   96);
    transpose_cast<<<dim3( 64,  2), 256, 0, stream>>>(W_dt,    W_dtT,      64, 2048);
    transpose_cast<<<dim3( 32, 64), 256, 0, stream>>>(W_out,   W_outT,   2048, 1024);
    cast_bf16<<<dim3(2048), 256, 0, stream>>>(x, x16, 524288);

    // 1) xz = x @ W_in              (4096 x 4096, K=1024) -> bf16, 8-phase
    gemm_8ph<1><<<dim3(256), 512, 0, stream>>>(
        x16, W_inT, xz16, MT, 4096, 1024, 1024, 4096, 1024);

    // 2) xc16 = silu(causal_dwconv(xin) + b)
    conv_silu_v2<<<dim3(8, 64, 2), 256, 0, stream>>>(xz16, conv_w, conv_b, xc16);

    // 3) dbc = xc @ W_xproj         (4096 x 96, K=2048) — split-K x8
    gemm_bt_lds<0, 0><<<dim3(1, 32, 8), 256, 0, stream>>>(
        xc16, W_xprojT, parts, nullptr, MT, 96, 2048, 2048, 2048, 96, 256);
    reduce_splitk<<<dim3(1536), 256, 0, stream>>>(parts, dbc, dtlo16, MT * 96, 8);

    // 4) delta = softplus(dt_lo @ W_dt + b_dt)  (4096 x 2048, K=64) — fast softplus
    gemm_bt_lds<1, 0><<<dim3(16, 32), 256, 0, stream>>>(
        dtlo16, W_dtT, delta, b_dt, MT, 2048, 64, 64, 64, 2048, 64);

    // 5) chunked selective scan + fused gate (bf16 y out), 2-way state split
    scan_pass1<<<dim3(2048), 256, 0, stream>>>(xc16, delta, dbc, A_log, Pbuf, Ebuf);
    scan_pass2<<<dim3(256), 256, 0, stream>>>(Pbuf, Ebuf);
    scan_pass3<<<dim3(2048), 256, 0, stream>>>(xc16, delta, dbc, A_log, D_skip,
                                               Ebuf, xz16, yb16);

    // 6) out = y @ W_out   (4096 x 1024, K=2048) — 8-phase, split-K x4
    //    ldb = 2048 (W_outT row stride = K).
    gemm_8ph<0><<<dim3(64, 1, 4), 512, 0, stream>>>(
        yb16, W_outT, parts6, MT, 1024, 2048, 2048, 1024, 512);
    reduce4<<<dim3(4096), 256, 0, stream>>>(parts6, out, MT * 1024 / 4);
}

// Round 5
// 307.526 us; speedup vs baseline: 1.0629x; 1.0102x over previous
//
#include <hip/hip_runtime.h>
#include <math.h>

#define B_SZ 2
#define L_SZ 2048
#define DMODEL 1024
#define DINNER 2048
#define DSTATE 16
#define DCONV 4
#define DTRANK 64

#define CS 32                    // scan chunk size
#define NCH (L_SZ / CS)          // 64 chunks per batch

typedef float f32x4 __attribute__((ext_vector_type(4)));
typedef float f32x2 __attribute__((ext_vector_type(2)));
typedef __bf16 bf16x8 __attribute__((ext_vector_type(8)));

__device__ __forceinline__ float silu_f(float x) {
    return x / (1.0f + __expf(-x));
}

// fast softplus: max(x,0) + log(1+exp(-|x|)); abs err ~1e-6, branch-free tails
__device__ __forceinline__ float softplus_f(float x) {
    return fmaxf(x, 0.0f) + __logf(1.0f + __expf(-fabsf(x)));
}

// raw v_exp_f32: computes 2^x (hardware trans op, no pre-multiply)
__device__ __forceinline__ float fexp2(float x) {
    float r;
    asm("v_exp_f32 %0, %1" : "=v"(r) : "v"(x));
    return r;
}

// fp32 -> bf16 round-to-nearest-even on raw bits
__device__ __forceinline__ unsigned short f2bf(float x) {
    unsigned int u = __float_as_uint(x);
    u = u + 0x7FFFu + ((u >> 16) & 1u);
    return (unsigned short)(u >> 16);
}

__device__ __forceinline__ float bf2f(unsigned short s) {
    return __uint_as_float(((unsigned int)s) << 16);
}

// async global->LDS DMA, 16B per lane; deposits at base + lane*16B.
__device__ __forceinline__ void gload_lds16(const unsigned short* g, unsigned short* l) {
    __builtin_amdgcn_global_load_lds(
        (const __attribute__((address_space(1))) void*)g,
        (__attribute__((address_space(3))) void*)l, 16, 0, 0);
}

union Pack8 { unsigned short s[8]; uint4 v; };

// Transpose + cast: W[R,C] fp32 -> WT[C,R] bf16. Grid (C/32, R/32), 256 thr.
__global__ __launch_bounds__(256) void transpose_cast(
    const float* __restrict__ W, unsigned short* __restrict__ WT, int R, int C)
{
    __shared__ float t[32][33];
    const int tx = threadIdx.x & 31;
    const int ty = threadIdx.x >> 5;
    const int r0 = blockIdx.y * 32;
    const int c0 = blockIdx.x * 32;
    #pragma unroll
    for (int i = 0; i < 4; i++)
        t[ty + i * 8][tx] = W[(r0 + ty + i * 8) * C + c0 + tx];
    __syncthreads();
    #pragma unroll
    for (int i = 0; i < 4; i++)
        WT[(c0 + ty + i * 8) * R + r0 + tx] = f2bf(t[tx][ty + i * 8]);
}

// cast fp32 -> bf16, 8 elems/thread
__global__ __launch_bounds__(256) void cast_bf16(
    const float* __restrict__ src, unsigned short* __restrict__ dst, int n8)
{
    int i = blockIdx.x * 256 + threadIdx.x;
    if (i >= n8) return;
    const float4 f0 = *(const float4*)(src + i * 8);
    const float4 f1 = *(const float4*)(src + i * 8 + 4);
    Pack8 p;
    p.s[0] = f2bf(f0.x); p.s[1] = f2bf(f0.y); p.s[2] = f2bf(f0.z); p.s[3] = f2bf(f0.w);
    p.s[4] = f2bf(f1.x); p.s[5] = f2bf(f1.y); p.s[6] = f2bf(f1.z); p.s[7] = f2bf(f1.w);
    *(uint4*)(dst + i * 8) = p.v;
}

// ---- bf16 MFMA GEMM, B pre-transposed, global_load_lds staging -------------
// (128x128 2-phase kernel, kept for the small GEMMs 3 and 4.)
template <int ACT, int OBF16>
__global__ __launch_bounds__(256) void gemm_bt_lds(
    const unsigned short* __restrict__ A, const unsigned short* __restrict__ BT,
    void* __restrict__ Cout, const float* __restrict__ bias,
    int M, int N, int K, int lda, int ldb, int ldc, int Kc)
{
    __shared__ unsigned short As[128 * 64];
    __shared__ unsigned short Bs[128 * 64];

    const int tid  = threadIdx.x;
    const int lane = tid & 63;
    const int wave = tid >> 6;
    const int wm   = wave >> 1;
    const int wn   = wave & 1;
    const int row0 = blockIdx.y * 128;
    const int col0 = blockIdx.x * 128;
    const int lq   = lane >> 4;
    const int lm   = lane & 15;
    const int kbeg = blockIdx.z * Kc;

    const int rloc = wave * 32 + (lane >> 3);
    const int sc   = (lane & 7) ^ ((lane >> 3) & 7);
    const unsigned short* gA = A + (size_t)(row0 + rloc) * lda + sc * 8;
    const unsigned short* gBp[4];
    #pragma unroll
    for (int is = 0; is < 4; is++) {
        int br = col0 + rloc + 8 * is;
        if (br > N - 1) br = N - 1;
        gBp[is] = BT + (size_t)br * ldb + sc * 8;
    }
    unsigned short* lA = As + wave * 2048;
    unsigned short* lB = Bs + wave * 2048;

    f32x4 acc[4][4];
    #pragma unroll
    for (int i = 0; i < 4; i++)
        #pragma unroll
        for (int j = 0; j < 4; j++)
            #pragma unroll
            for (int r = 0; r < 4; r++) acc[i][j][r] = 0.0f;

    for (int k0 = kbeg; k0 < kbeg + Kc; k0 += 64) {
        #pragma unroll
        for (int is = 0; is < 4; is++) {
            gload_lds16(gA + (size_t)(8 * is) * lda + k0, lA + is * 512);
            gload_lds16(gBp[is] + k0, lB + is * 512);
        }
        __syncthreads();

        #pragma unroll
        for (int ks = 0; ks < 2; ks++) {
            bf16x8 af[4], bfr[4];
            #pragma unroll
            for (int i = 0; i < 4; i++) {
                int row = wm * 64 + i * 16 + lm;
                af[i] = *(const bf16x8*)&As[row * 64 + (((ks * 4 + lq) ^ (row & 7)) * 8)];
            }
            #pragma unroll
            for (int j = 0; j < 4; j++) {
                int row = wn * 64 + j * 16 + lm;
                bfr[j] = *(const bf16x8*)&Bs[row * 64 + (((ks * 4 + lq) ^ (row & 7)) * 8)];
            }
            #pragma unroll
            for (int i = 0; i < 4; i++)
                #pragma unroll
                for (int j = 0; j < 4; j++)
                    acc[i][j] = __builtin_amdgcn_mfma_f32_16x16x32_bf16(
                        af[i], bfr[j], acc[i][j], 0, 0, 0);
        }
        __syncthreads();
    }

    // epilogue: C/D layout col=lane&15, row=(lane>>4)*4+reg
    #pragma unroll
    for (int i = 0; i < 4; i++) {
        #pragma unroll
        for (int r = 0; r < 4; r++) {
            int row = row0 + wm * 64 + i * 16 + lq * 4 + r;
            #pragma unroll
            for (int j = 0; j < 4; j++) {
                int col = col0 + wn * 64 + j * 16 + lm;
                if (col < N) {
                    float v = acc[i][j][r];
                    if (ACT == 1) v = softplus_f(v + bias[col]);
                    if (OBF16) {
                        unsigned short* Cz = (unsigned short*)Cout +
                            (size_t)blockIdx.z * (size_t)M * ldc;
                        Cz[(size_t)row * ldc + col] = f2bf(v);
                    } else {
                        float* Cz = (float*)Cout +
                            (size_t)blockIdx.z * (size_t)M * ldc;
                        Cz[(size_t)row * ldc + col] = v;
                    }
                }
            }
        }
    }
}

// ---- 256x256 8-phase bf16 GEMM (m201-style), counted vmcnt + setprio -------
// 512 thr = 8 waves (2M x 4N), per-wave 128x64 out, BK=64, NT = Kc/64 K-tiles.
// LDS 128KB: sm[buf][A|B][unit:4][64x64 bf16]. XOR-swizzled (rule #21).
// Staging calendar per tile t (2 units/phase), one vmcnt(4) per K-tile.
template <int OBF16>
__global__ __launch_bounds__(512, 2) void gemm_8ph(
    const unsigned short* __restrict__ A, const unsigned short* __restrict__ BT,
    void* __restrict__ Cout, int M, int N, int lda, int ldb, int ldc, int Kc)
{
    __shared__ unsigned short sm[2][2][4][64 * 64];

    const int tid  = threadIdx.x;
    const int lane = tid & 63;
    const int wave = tid >> 6;         // 0..7
    const int wm   = wave >> 2;        // 0..1  (128-row half)
    const int wn   = wave & 3;         // 0..3  (64-col quarter)
    const int lq   = lane >> 4;
    const int lm   = lane & 15;

    // bijective XCD swizzle (gridDim.x % 8 == 0 guaranteed by caller)
    const int cpx = gridDim.x >> 3;
    const int ti  = (blockIdx.x & 7) * cpx + (blockIdx.x >> 3);
    const int nbx = N >> 8;
    const int row0 = (ti / nbx) * 256;
    const int col0 = (ti % nbx) * 256;
    const int kbeg = blockIdx.z * Kc;

    // staging: one gload per thread per 64-row unit (512 thr x 16B = 8KB)
    const int r  = tid >> 3;                 // row within unit, 0..63
    const int sc = (tid & 7) ^ (r & 7);      // pre-swizzled source group
    const unsigned short* gA = A + (size_t)(row0 + r) * lda + sc * 8 + kbeg;
    const unsigned short* gB[4];
    #pragma unroll
    for (int u = 0; u < 4; u++) {
        int br = col0 + u * 64 + r;
        if (br > N - 1) br = N - 1;
        gB[u] = BT + (size_t)br * ldb + sc * 8 + kbeg;
    }

    #define STA(bsel, u, kk) gload_lds16(gA + (size_t)((u) * 64) * lda + (kk), \
                                         &sm[bsel][0][u][wave * 512])
    #define STB(bsel, u, kk) gload_lds16(gB[u] + (kk), &sm[bsel][1][u][wave * 512])

    f32x4 acc[8][4];
    #pragma unroll
    for (int i = 0; i < 8; i++)
        #pragma unroll
        for (int j = 0; j < 4; j++)
            #pragma unroll
            for (int rr = 0; rr < 4; rr++) acc[i][j][rr] = 0.0f;

    const int NT = Kc >> 6;
    // prologue, exact issue order (oldest->newest) matched to vmcnt(4) math:
    // [0.b0 0.b1][0.a0 0.a2][0.a1 0.a3][0.b2 0.b3][1.b0 1.b1][1.a0 1.a2]
    STB(0, 0, 0); STB(0, 1, 0); STA(0, 0, 0); STA(0, 2, 0);
    STA(0, 1, 0); STA(0, 3, 0); STB(0, 2, 0); STB(0, 3, 0);
    if (NT > 1) { STB(1, 0, 64); STB(1, 1, 64); STA(1, 0, 64); STA(1, 2, 64); }

    bf16x8 bq[4][2];

    for (int t = 0; t < NT; ++t) {
        const int b   = t & 1;
        const int kk1 = (t + 1) * 64;
        const int kk2 = (t + 2) * 64;

        if (t == NT - 1) asm volatile("s_waitcnt vmcnt(0)" ::: "memory");
        else             asm volatile("s_waitcnt vmcnt(4)" ::: "memory");
        __builtin_amdgcn_s_barrier();
        __builtin_amdgcn_sched_barrier(0);

        #pragma unroll
        for (int q = 0; q < 4; ++q) {
            bf16x8 af2[2][2];
            #pragma unroll
            for (int ii = 0; ii < 2; ii++) {
                int br = wm * 128 + (2 * q + ii) * 16 + lm;
                #pragma unroll
                for (int ks = 0; ks < 2; ks++)
                    af2[ii][ks] = *(const bf16x8*)&sm[b][0][br >> 6]
                        [(br & 63) * 64 + (((ks * 4 + lq) ^ (br & 7)) * 8)];
            }
            if (q == 0) {
                #pragma unroll
                for (int j = 0; j < 4; j++) {
                    int br = wn * 64 + j * 16 + lm;
                    #pragma unroll
                    for (int ks = 0; ks < 2; ks++)
                        bq[j][ks] = *(const bf16x8*)&sm[b][1][br >> 6]
                            [(br & 63) * 64 + (((ks * 4 + lq) ^ (br & 7)) * 8)];
                }
            }
            // staging calendar (2 units / phase)
            if (q == 0 && t + 1 < NT) { STA(b ^ 1, 1, kk1); STA(b ^ 1, 3, kk1); }
            if (q == 1 && t + 1 < NT) { STB(b ^ 1, 2, kk1); STB(b ^ 1, 3, kk1); }
            if (q == 2 && t + 2 < NT) { STB(b, 0, kk2); STB(b, 1, kk2); }
            if (q == 3 && t + 2 < NT) { STA(b, 0, kk2); STA(b, 2, kk2); }

            asm volatile("s_waitcnt lgkmcnt(0)" ::: "memory");
            __builtin_amdgcn_sched_barrier(0);
            __builtin_amdgcn_s_setprio(1);
            #pragma unroll
            for (int ii = 0; ii < 2; ii++)
                #pragma unroll
                for (int j = 0; j < 4; j++) {
                    acc[2 * q + ii][j] = __builtin_amdgcn_mfma_f32_16x16x32_bf16(
                        af2[ii][0], bq[j][0], acc[2 * q + ii][j], 0, 0, 0);
                    acc[2 * q + ii][j] = __builtin_amdgcn_mfma_f32_16x16x32_bf16(
                        af2[ii][1], bq[j][1], acc[2 * q + ii][j], 0, 0, 0);
                }
            __builtin_amdgcn_s_setprio(0);
            __builtin_amdgcn_sched_barrier(0);
            if (q < 3) {
                __builtin_amdgcn_s_barrier();
                __builtin_amdgcn_sched_barrier(0);
            }
        }
    }
    #undef STA
    #undef STB

    // epilogue: C/D layout col=lane&15, row=(lane>>4)*4+reg
    const size_t zoff = (size_t)blockIdx.z * (size_t)M * ldc;
    #pragma unroll
    for (int i = 0; i < 8; i++) {
        #pragma unroll
        for (int rr = 0; rr < 4; rr++) {
            int row = row0 + wm * 128 + i * 16 + lq * 4 + rr;
            #pragma unroll
            for (int j = 0; j < 4; j++) {
                int col = col0 + wn * 64 + j * 16 + lm;
                if (col < N) {
                    float v = acc[i][j][rr];
                    if (OBF16)
                        ((unsigned short*)Cout)[(size_t)row * ldc + col] = f2bf(v);
                    else
                        ((float*)Cout)[zoff + (size_t)row * ldc + col] = v;
                }
            }
        }
    }
}

// Sum nsplit partial C buffers; also emit bf16 copy of cols<64 (dt_lo).
__global__ __launch_bounds__(256) void reduce_splitk(
    const float* __restrict__ part, float* __restrict__ C,
    unsigned short* __restrict__ dtlo16, int n, int nsplit)
{
    int i = blockIdx.x * 256 + threadIdx.x;
    if (i >= n) return;
    float s = 0.0f;
    for (int z = 0; z < nsplit; z++) s += part[(size_t)z * n + i];
    C[i] = s;
    int row = i / 96;
    int col = i - row * 96;
    if (col < DTRANK) dtlo16[row * DTRANK + col] = f2bf(s);
}

// Sum 4 fp32 partials, vectorized. n4 = total_floats/4.
__global__ __launch_bounds__(256) void reduce4(
    const float* __restrict__ part, float* __restrict__ out, int n4)
{
    int i = blockIdx.x * 256 + threadIdx.x;
    if (i >= n4) return;
    const f32x4* p = (const f32x4*)part;
    f32x4 s = p[i];
    s += p[i + n4];
    s += p[i + 2 * n4];
    s += p[i + 3 * n4];
    ((f32x4*)out)[i] = s;
}

// conv + silu, register-rolling window along l. Reads bf16 xz (cols 0..2048),
// emits bf16 xc16. grid (8, 64, 2).
__global__ __launch_bounds__(256) void conv_silu_v2(
    const unsigned short* __restrict__ xz16, const float* __restrict__ conv_w,
    const float* __restrict__ conv_b, unsigned short* __restrict__ xc16)
{
    const int tid = threadIdx.x;
    const int d   = blockIdx.x * 256 + tid;
    const int l0  = blockIdx.y * 32;
    const int b   = blockIdx.z;
    const float4 w  = *(const float4*)(conv_w + d * 4);
    const float bias = conv_b[d];
    const int t0 = b * L_SZ + l0;
    const unsigned short* src = xz16 + (size_t)t0 * 4096 + d;

    float r0, r1, r2;
    if (l0 == 0) {
        r0 = r1 = r2 = 0.0f;
    } else {
        r0 = bf2f(src[-3 * 4096]);
        r1 = bf2f(src[-2 * 4096]);
        r2 = bf2f(src[-1 * 4096]);
    }
    #pragma unroll 4
    for (int l = 0; l < 32; l++) {
        float r3 = bf2f(src[(size_t)l * 4096]);
        float acc = bias + r0 * w.x + r1 * w.y + r2 * w.z + r3 * w.w;
        xc16[(size_t)(t0 + l) * DINNER + d] = f2bf(silu_f(acc));
        r0 = r1; r1 = r2; r2 = r3;
    }
}

// ---- Chunked parallel selective scan (CS=32, 1024 blocks) -------------------
// v4: back to 16 states/thread (v3 split REGRESSED: duplicated issue work).
// Math core minimized for VALU issue:
//   - A2[s] = -log2e*exp(A_log): dA = v_exp_f32(dv*A2) directly (no per-exp mul)
//   - f32x2 packed h/Er update -> v_pk_mul/v_pk_fma_f32 (half the VALU ops)
//   - pass3: 4 parallel yv chains (2 x f32x2) instead of 16-deep serial FMA
// grid: B * NCH * 8 = 1024; db=blk&7, c=(blk>>3)&63, b=blk>>9.
__global__ __launch_bounds__(256) void scan_pass1(
    const unsigned short* __restrict__ xc16, const float* __restrict__ delta,
    const float* __restrict__ dbc, const float* __restrict__ A_log,
    float* __restrict__ P, float* __restrict__ E)
{
    __shared__ float Bs[CS * DSTATE];
    const int tid = threadIdx.x;
    const int db  = blockIdx.x & 7;
    const int c   = (blockIdx.x >> 3) & (NCH - 1);
    const int b   = blockIdx.x >> 9;
    const int d   = db * 256 + tid;
    const int t0  = b * L_SZ + c * CS;

    for (int idx = tid; idx < CS * DSTATE; idx += 256) {
        int step = idx >> 4, i = idx & 15;
        Bs[idx] = dbc[(t0 + step) * 96 + DTRANK + i];
    }

    f32x2 A2v[8], Er2[8];
    const float* Ap = A_log + d * DSTATE;
    #pragma unroll
    for (int p = 0; p < 8; p++) {
        A2v[p].x = -1.44269504f * __expf(Ap[2 * p]);
        A2v[p].y = -1.44269504f * __expf(Ap[2 * p + 1]);
        Er2[p].x = 0.0f; Er2[p].y = 0.0f;
    }
    float sd = 0.0f;

    const float* dp = delta + (size_t)t0 * DINNER + d;
    const unsigned short* up = xc16 + (size_t)t0 * DINNER + d;

    float dv[4], uv[4];
    #pragma unroll
    for (int q = 0; q < 4; q++) {
        dv[q] = dp[(size_t)q * DINNER];
        uv[q] = bf2f(up[(size_t)q * DINNER]);
    }
    __syncthreads();

    for (int lo = 0; lo < CS; lo += 4) {
        float nd[4], nu[4];
        if (lo + 4 < CS) {
            #pragma unroll
            for (int q = 0; q < 4; q++) {
                nd[q] = dp[(size_t)(lo + 4 + q) * DINNER];
                nu[q] = bf2f(up[(size_t)(lo + 4 + q) * DINNER]);
            }
        }
        #pragma unroll
        for (int q = 0; q < 4; q++) {
            const float dvq = dv[q];
            const float du  = dvq * uv[q];
            sd += dvq;
            const f32x4* Bv = (const f32x4*)&Bs[(lo + q) * DSTATE];
            f32x4 b0 = Bv[0], b1 = Bv[1], b2 = Bv[2], b3 = Bv[3];
            #define P1PAIR(p, bb) { \
                f32x2 m = dvq * A2v[p]; \
                f32x2 e; e.x = fexp2(m.x); e.y = fexp2(m.y); \
                Er2[p] = e * Er2[p] + du * (bb); }
            P1PAIR(0, b0.xy) P1PAIR(1, b0.zw)
            P1PAIR(2, b1.xy) P1PAIR(3, b1.zw)
            P1PAIR(4, b2.xy) P1PAIR(5, b2.zw)
            P1PAIR(6, b3.xy) P1PAIR(7, b3.zw)
            #undef P1PAIR
        }
        #pragma unroll
        for (int q = 0; q < 4; q++) { dv[q] = nd[q]; uv[q] = nu[q]; }
    }

    const long long o = ((long long)((b * NCH + c) * DINNER) + d) * DSTATE;
    #pragma unroll
    for (int w = 0; w < 4; w++) {
        f32x4 pv, ev;
        #pragma unroll
        for (int k = 0; k < 2; k++) {
            int p = w * 2 + k;
            pv[2 * k]     = fexp2(A2v[p].x * sd);
            pv[2 * k + 1] = fexp2(A2v[p].y * sd);
            ev[2 * k]     = Er2[p].x;
            ev[2 * k + 1] = Er2[p].y;
        }
        *(f32x4*)(P + o + w * 4) = pv;
        *(f32x4*)(E + o + w * 4) = ev;
    }
}

__global__ __launch_bounds__(256) void scan_pass2(
    const float* __restrict__ P, float* __restrict__ E)
{
    const int gid  = blockIdx.x * 256 + threadIdx.x;
    const int b    = gid >> 15;
    const int rest = gid & 32767;
    float h = 0.0f;
    for (int c = 0; c < NCH; c++) {
        const long long idx = (long long)(b * NCH + c) * (DINNER * DSTATE) + rest;
        float p = P[idx];
        float e = E[idx];
        E[idx] = h;
        h = p * h + e;
    }
}

// pass3 v4: packed math (see pass1), fused silu(z) gate, bf16 y out.
__global__ __launch_bounds__(256) void scan_pass3(
    const unsigned short* __restrict__ xc16, const float* __restrict__ delta,
    const float* __restrict__ dbc, const float* __restrict__ A_log,
    const float* __restrict__ D_skip, const float* __restrict__ Hin,
    const unsigned short* __restrict__ xz16, unsigned short* __restrict__ y16)
{
    __shared__ float BCs[CS * 2 * DSTATE];
    const int tid = threadIdx.x;
    const int db  = blockIdx.x & 7;
    const int c   = (blockIdx.x >> 3) & (NCH - 1);
    const int b   = blockIdx.x >> 9;
    const int d   = db * 256 + tid;
    const int t0  = b * L_SZ + c * CS;

    for (int idx = tid; idx < CS * 2 * DSTATE; idx += 256) {
        int step = idx >> 5, i = idx & 31;
        BCs[idx] = dbc[(t0 + step) * 96 + DTRANK + i];
    }

    f32x2 A2v[8], h2[8];
    const float* Ap = A_log + d * DSTATE;
    const long long o = ((long long)((b * NCH + c) * DINNER) + d) * DSTATE;
    #pragma unroll
    for (int p = 0; p < 8; p++) {
        A2v[p].x = -1.44269504f * __expf(Ap[2 * p]);
        A2v[p].y = -1.44269504f * __expf(Ap[2 * p + 1]);
        h2[p].x = Hin[o + 2 * p];
        h2[p].y = Hin[o + 2 * p + 1];
    }
    const float Dv = D_skip[d];

    const float* dp = delta + (size_t)t0 * DINNER + d;
    const unsigned short* up = xc16 + (size_t)t0 * DINNER + d;
    const unsigned short* zp = xz16 + (size_t)t0 * 4096 + DINNER + d;
    unsigned short* yp = y16 + (size_t)t0 * DINNER + d;

    float dv[4], uv[4], zv[4];
    #pragma unroll
    for (int q = 0; q < 4; q++) {
        dv[q] = dp[(size_t)q * DINNER];
        uv[q] = bf2f(up[(size_t)q * DINNER]);
        zv[q] = bf2f(zp[(size_t)q * 4096]);
    }
    __syncthreads();

    for (int lo = 0; lo < CS; lo += 4) {
        float nd[4], nu[4], nz[4];
        if (lo + 4 < CS) {
            #pragma unroll
            for (int q = 0; q < 4; q++) {
                nd[q] = dp[(size_t)(lo + 4 + q) * DINNER];
                nu[q] = bf2f(up[(size_t)(lo + 4 + q) * DINNER]);
                nz[q] = bf2f(zp[(size_t)(lo + 4 + q) * 4096]);
            }
        }
        #pragma unroll
        for (int q = 0; q < 4; q++) {
            const float dvq = dv[q];
            const float uvq = uv[q];
            const float du  = dvq * uvq;
            const f32x4* Bv = (const f32x4*)&BCs[(lo + q) * 32];
            f32x4 b0 = Bv[0], b1 = Bv[1], b2 = Bv[2], b3 = Bv[3];
            f32x4 c0 = Bv[4], c1 = Bv[5], c2 = Bv[6], c3 = Bv[7];
            f32x2 y0; y0.x = 0.0f; y0.y = 0.0f;
            f32x2 y1; y1.x = 0.0f; y1.y = 0.0f;
            #define P3PAIR(p, bb, cc, ya) { \
                f32x2 m = dvq * A2v[p]; \
                f32x2 e; e.x = fexp2(m.x); e.y = fexp2(m.y); \
                h2[p] = e * h2[p] + du * (bb); \
                ya = ya + h2[p] * (cc); }
            P3PAIR(0, b0.xy, c0.xy, y0) P3PAIR(1, b0.zw, c0.zw, y1)
            P3PAIR(2, b1.xy, c1.xy, y0) P3PAIR(3, b1.zw, c1.zw, y1)
            P3PAIR(4, b2.xy, c2.xy, y0) P3PAIR(5, b2.zw, c2.zw, y1)
            P3PAIR(6, b3.xy, c3.xy, y0) P3PAIR(7, b3.zw, c3.zw, y1)
            #undef P3PAIR
            f32x2 ys = y0 + y1;
            float yv = ys.x + ys.y;
            yp[(size_t)(lo + q) * DINNER] = f2bf((uvq * Dv + yv) * silu_f(zv[q]));
        }
        #pragma unroll
        for (int q = 0; q < 4; q++) { dv[q] = nd[q]; uv[q] = nu[q]; zv[q] = nz[q]; }
    }
}

extern "C" void kernel_launch(void* const* d_in, const int* in_sizes, int n_in,
                              void* d_out, int out_size, void* d_ws, size_t ws_size,
                              hipStream_t stream) {
    const float* x       = (const float*)d_in[0];
    const float* W_in    = (const float*)d_in[1];
    const float* conv_w  = (const float*)d_in[2];
    const float* conv_b  = (const float*)d_in[3];
    const float* W_xproj = (const float*)d_in[4];
    const float* W_dt    = (const float*)d_in[5];
    const float* b_dt    = (const float*)d_in[6];
    const float* A_log   = (const float*)d_in[7];
    const float* D_skip  = (const float*)d_in[8];
    const float* W_out   = (const float*)d_in[9];
    float* out = (float*)d_out;

    // workspace layout, float units (141 MB). Aliases (dead-before-reuse):
    //   parts (dead after reduce) shares Pbuf (written at pass1)
    //   x16 (dead after gemm1)    shares yb16 (written at pass3)
    //   parts6 (GEMM6 split-K partials, 64MB) spans delta..Pbuf — all dead
    //   after pass3; GEMM6/reduce4 run after pass3. 16777216 f exactly. ✓
    float* ws = (float*)d_ws;
    unsigned short* xz16   = (unsigned short*)ws;              // [0 .. 8388608) f
    unsigned short* xc16   = (unsigned short*)(ws +  8388608); // [.. 12582912) f
    float* dbc             = ws + 12582912;                    // [.. 12976128) f
    unsigned short* dtlo16 = (unsigned short*)(ws + 12976128); // [.. 13107200) f
    float* delta           = ws + 13107200;                    // [.. 21495808) f
    float* Ebuf            = ws + 21495808;                    // [.. 25690112) f : 2*64*2048*16
    float* Pbuf            = ws + 25690112;                    // [.. 29884416) f : 2*64*2048*16
    float* parts           = Pbuf;                             //   alias, 3145728 f < 4194304 ✓
    float* parts6          = delta;                            //   alias, 4*4096*1024 = 16777216 f ✓
    unsigned short* yb16   = (unsigned short*)(ws + 29884416); // [.. 31981568) f
    unsigned short* x16    = yb16;                             //   alias
    unsigned short* W_inT    = (unsigned short*)(ws + 31981568); // [.. 34078720) f
    unsigned short* W_xprojT = (unsigned short*)(ws + 34078720); // [.. 34177024) f
    unsigned short* W_dtT    = (unsigned short*)(ws + 34177024); // [.. 34242560) f
    unsigned short* W_outT   = (unsigned short*)(ws + 34242560); // [.. 35291136) f

    const int MT = 4096;  // B*L tokens

    transpose_cast<<<dim3(128, 32), 256, 0, stream>>>(W_in,    W_inT,    1024, 4096);
    transpose_cast<<<dim3(  3, 64), 256, 0, stream>>>(W_xproj, W_xprojT, 2048,   96);
    transpose_cast<<<dim3( 64,  2), 256, 0, stream>>>(W_dt,    W_dtT,      64, 2048);
    transpose_cast<<<dim3( 32, 64), 256, 0, stream>>>(W_out,   W_outT,   2048, 1024);
    cast_bf16<<<dim3(2048), 256, 0, stream>>>(x, x16, 524288);

    // 1) xz = x @ W_in              (4096 x 4096, K=1024) -> bf16, 8-phase
    gemm_8ph<1><<<dim3(256), 512, 0, stream>>>(
        x16, W_inT, xz16, MT, 4096, 1024, 1024, 4096, 1024);

    // 2) xc16 = silu(causal_dwconv(xin) + b)
    conv_silu_v2<<<dim3(8, 64, 2), 256, 0, stream>>>(xz16, conv_w, conv_b, xc16);

    // 3) dbc = xc @ W_xproj         (4096 x 96, K=2048) — split-K x8
    gemm_bt_lds<0, 0><<<dim3(1, 32, 8), 256, 0, stream>>>(
        xc16, W_xprojT, parts, nullptr, MT, 96, 2048, 2048, 2048, 96, 256);
    reduce_splitk<<<dim3(1536), 256, 0, stream>>>(parts, dbc, dtlo16, MT * 96, 8);

    // 4) delta = softplus(dt_lo @ W_dt + b_dt)  (4096 x 2048, K=64) — fast softplus
    gemm_bt_lds<1, 0><<<dim3(16, 32), 256, 0, stream>>>(
        dtlo16, W_dtT, delta, b_dt, MT, 2048, 64, 64, 64, 2048, 64);

    // 5) chunked selective scan + fused gate (bf16 y out), packed math v4
    scan_pass1<<<dim3(1024), 256, 0, stream>>>(xc16, delta, dbc, A_log, Pbuf, Ebuf);
    scan_pass2<<<dim3(256), 256, 0, stream>>>(Pbuf, Ebuf);
    scan_pass3<<<dim3(1024), 256, 0, stream>>>(xc16, delta, dbc, A_log, D_skip,
                                               Ebuf, xz16, yb16);

    // 6) out = y @ W_out   (4096 x 1024, K=2048) — 8-phase, split-K x4
    //    ldb = 2048 (W_outT row stride = K).
    gemm_8ph<0><<<dim3(64, 1, 4), 512, 0, stream>>>(
        yb16, W_outT, parts6, MT, 1024, 2048, 2048, 1024, 512);
    reduce4<<<dim3(4096), 256, 0, stream>>>(parts6, out, MT * 1024 / 4);
}

// Round 6
// 302.421 us; speedup vs baseline: 1.0808x; 1.0169x over previous
//
#include <hip/hip_runtime.h>
#include <math.h>

#define B_SZ 2
#define L_SZ 2048
#define DMODEL 1024
#define DINNER 2048
#define DSTATE 16
#define DCONV 4
#define DTRANK 64

#define CS 32                    // scan chunk size
#define NCH (L_SZ / CS)          // 64 chunks per batch

typedef float f32x4 __attribute__((ext_vector_type(4)));
typedef float f32x2 __attribute__((ext_vector_type(2)));
typedef __bf16 bf16x8 __attribute__((ext_vector_type(8)));

__device__ __forceinline__ float silu_f(float x) {
    return x / (1.0f + __expf(-x));
}

// fast softplus: max(x,0) + log(1+exp(-|x|)); abs err ~1e-6, branch-free tails
__device__ __forceinline__ float softplus_f(float x) {
    return fmaxf(x, 0.0f) + __logf(1.0f + __expf(-fabsf(x)));
}

// raw v_exp_f32: computes 2^x (hardware trans op, no pre-multiply)
__device__ __forceinline__ float fexp2(float x) {
    float r;
    asm("v_exp_f32 %0, %1" : "=v"(r) : "v"(x));
    return r;
}

// fp32 -> bf16 round-to-nearest-even on raw bits
__device__ __forceinline__ unsigned short f2bf(float x) {
    unsigned int u = __float_as_uint(x);
    u = u + 0x7FFFu + ((u >> 16) & 1u);
    return (unsigned short)(u >> 16);
}

__device__ __forceinline__ float bf2f(unsigned short s) {
    return __uint_as_float(((unsigned int)s) << 16);
}

// async global->LDS DMA, 16B per lane; deposits at base + lane*16B.
__device__ __forceinline__ void gload_lds16(const unsigned short* g, unsigned short* l) {
    __builtin_amdgcn_global_load_lds(
        (const __attribute__((address_space(1))) void*)g,
        (__attribute__((address_space(3))) void*)l, 16, 0, 0);
}

union Pack8 { unsigned short s[8]; uint4 v; };

// Transpose + cast: W[R,C] fp32 -> WT[C,R] bf16. Grid (C/32, R/32), 256 thr.
__global__ __launch_bounds__(256) void transpose_cast(
    const float* __restrict__ W, unsigned short* __restrict__ WT, int R, int C)
{
    __shared__ float t[32][33];
    const int tx = threadIdx.x & 31;
    const int ty = threadIdx.x >> 5;
    const int r0 = blockIdx.y * 32;
    const int c0 = blockIdx.x * 32;
    #pragma unroll
    for (int i = 0; i < 4; i++)
        t[ty + i * 8][tx] = W[(r0 + ty + i * 8) * C + c0 + tx];
    __syncthreads();
    #pragma unroll
    for (int i = 0; i < 4; i++)
        WT[(c0 + ty + i * 8) * R + r0 + tx] = f2bf(t[tx][ty + i * 8]);
}

// cast fp32 -> bf16, 8 elems/thread
__global__ __launch_bounds__(256) void cast_bf16(
    const float* __restrict__ src, unsigned short* __restrict__ dst, int n8)
{
    int i = blockIdx.x * 256 + threadIdx.x;
    if (i >= n8) return;
    const float4 f0 = *(const float4*)(src + i * 8);
    const float4 f1 = *(const float4*)(src + i * 8 + 4);
    Pack8 p;
    p.s[0] = f2bf(f0.x); p.s[1] = f2bf(f0.y); p.s[2] = f2bf(f0.z); p.s[3] = f2bf(f0.w);
    p.s[4] = f2bf(f1.x); p.s[5] = f2bf(f1.y); p.s[6] = f2bf(f1.z); p.s[7] = f2bf(f1.w);
    *(uint4*)(dst + i * 8) = p.v;
}

// ---- bf16 MFMA GEMM, B pre-transposed, global_load_lds staging -------------
// (128x128 2-phase kernel, kept for the small GEMMs 3 and 4.)
template <int ACT, int OBF16>
__global__ __launch_bounds__(256) void gemm_bt_lds(
    const unsigned short* __restrict__ A, const unsigned short* __restrict__ BT,
    void* __restrict__ Cout, const float* __restrict__ bias,
    int M, int N, int K, int lda, int ldb, int ldc, int Kc)
{
    __shared__ unsigned short As[128 * 64];
    __shared__ unsigned short Bs[128 * 64];

    const int tid  = threadIdx.x;
    const int lane = tid & 63;
    const int wave = tid >> 6;
    const int wm   = wave >> 1;
    const int wn   = wave & 1;
    const int row0 = blockIdx.y * 128;
    const int col0 = blockIdx.x * 128;
    const int lq   = lane >> 4;
    const int lm   = lane & 15;
    const int kbeg = blockIdx.z * Kc;

    const int rloc = wave * 32 + (lane >> 3);
    const int sc   = (lane & 7) ^ ((lane >> 3) & 7);
    const unsigned short* gA = A + (size_t)(row0 + rloc) * lda + sc * 8;
    const unsigned short* gBp[4];
    #pragma unroll
    for (int is = 0; is < 4; is++) {
        int br = col0 + rloc + 8 * is;
        if (br > N - 1) br = N - 1;
        gBp[is] = BT + (size_t)br * ldb + sc * 8;
    }
    unsigned short* lA = As + wave * 2048;
    unsigned short* lB = Bs + wave * 2048;

    f32x4 acc[4][4];
    #pragma unroll
    for (int i = 0; i < 4; i++)
        #pragma unroll
        for (int j = 0; j < 4; j++)
            #pragma unroll
            for (int r = 0; r < 4; r++) acc[i][j][r] = 0.0f;

    for (int k0 = kbeg; k0 < kbeg + Kc; k0 += 64) {
        #pragma unroll
        for (int is = 0; is < 4; is++) {
            gload_lds16(gA + (size_t)(8 * is) * lda + k0, lA + is * 512);
            gload_lds16(gBp[is] + k0, lB + is * 512);
        }
        __syncthreads();

        #pragma unroll
        for (int ks = 0; ks < 2; ks++) {
            bf16x8 af[4], bfr[4];
            #pragma unroll
            for (int i = 0; i < 4; i++) {
                int row = wm * 64 + i * 16 + lm;
                af[i] = *(const bf16x8*)&As[row * 64 + (((ks * 4 + lq) ^ (row & 7)) * 8)];
            }
            #pragma unroll
            for (int j = 0; j < 4; j++) {
                int row = wn * 64 + j * 16 + lm;
                bfr[j] = *(const bf16x8*)&Bs[row * 64 + (((ks * 4 + lq) ^ (row & 7)) * 8)];
            }
            #pragma unroll
            for (int i = 0; i < 4; i++)
                #pragma unroll
                for (int j = 0; j < 4; j++)
                    acc[i][j] = __builtin_amdgcn_mfma_f32_16x16x32_bf16(
                        af[i], bfr[j], acc[i][j], 0, 0, 0);
        }
        __syncthreads();
    }

    // epilogue: C/D layout col=lane&15, row=(lane>>4)*4+reg
    #pragma unroll
    for (int i = 0; i < 4; i++) {
        #pragma unroll
        for (int r = 0; r < 4; r++) {
            int row = row0 + wm * 64 + i * 16 + lq * 4 + r;
            #pragma unroll
            for (int j = 0; j < 4; j++) {
                int col = col0 + wn * 64 + j * 16 + lm;
                if (col < N) {
                    float v = acc[i][j][r];
                    if (ACT == 1) v = softplus_f(v + bias[col]);
                    if (OBF16) {
                        unsigned short* Cz = (unsigned short*)Cout +
                            (size_t)blockIdx.z * (size_t)M * ldc;
                        Cz[(size_t)row * ldc + col] = f2bf(v);
                    } else {
                        float* Cz = (float*)Cout +
                            (size_t)blockIdx.z * (size_t)M * ldc;
                        Cz[(size_t)row * ldc + col] = v;
                    }
                }
            }
        }
    }
}

// ---- 256x256 8-phase bf16 GEMM, pipelined LDS reads (v2) -------------------
// 512 thr = 8 waves (2M x 4N), per-wave 128x64 out, BK=64, NT = Kc/64 K-tiles.
// LDS 128KB: sm[buf][A|B][unit:4][64x64 bf16]. XOR-swizzled (rule #21).
// v2: ds_reads issued ONE PHASE AHEAD (afA/afB register dbuf) so their
// latency drains under the intra-tile barrier + other wave's MFMA.
// NO explicit lgkmcnt — compiler emits counted waits before MFMA use.
// Staging calendar per tile t (2 units/phase), one vmcnt(4) per K-tile:
//   q0: (t+1).a1,a3   q1: (t+1).b2,b3   q2: (t+2).b0,b1   q3: (t+2).a0,a2
// Hazards: bq retired before q0's MFMA (compiler wait) => before barriers
// preceding q2's b0/b1 stage. a1/a3 (read q2/q3) never staged within tile t.
template <int OBF16>
__global__ __launch_bounds__(512, 2) void gemm_8ph(
    const unsigned short* __restrict__ A, const unsigned short* __restrict__ BT,
    void* __restrict__ Cout, int M, int N, int lda, int ldb, int ldc, int Kc)
{
    __shared__ unsigned short sm[2][2][4][64 * 64];

    const int tid  = threadIdx.x;
    const int lane = tid & 63;
    const int wave = tid >> 6;         // 0..7
    const int wm   = wave >> 2;        // 0..1  (128-row half)
    const int wn   = wave & 3;         // 0..3  (64-col quarter)
    const int lq   = lane >> 4;
    const int lm   = lane & 15;

    // bijective XCD swizzle (gridDim.x % 8 == 0 guaranteed by caller)
    const int cpx = gridDim.x >> 3;
    const int ti  = (blockIdx.x & 7) * cpx + (blockIdx.x >> 3);
    const int nbx = N >> 8;
    const int row0 = (ti / nbx) * 256;
    const int col0 = (ti % nbx) * 256;
    const int kbeg = blockIdx.z * Kc;

    // staging: one gload per thread per 64-row unit (512 thr x 16B = 8KB)
    const int r  = tid >> 3;                 // row within unit, 0..63
    const int sc = (tid & 7) ^ (r & 7);      // pre-swizzled source group
    const unsigned short* gA = A + (size_t)(row0 + r) * lda + sc * 8 + kbeg;
    const unsigned short* gB[4];
    #pragma unroll
    for (int u = 0; u < 4; u++) {
        int br = col0 + u * 64 + r;
        if (br > N - 1) br = N - 1;
        gB[u] = BT + (size_t)br * ldb + sc * 8 + kbeg;
    }

    #define STA(bsel, u, kk) gload_lds16(gA + (size_t)((u) * 64) * lda + (kk), \
                                         &sm[bsel][0][u][wave * 512])
    #define STB(bsel, u, kk) gload_lds16(gB[u] + (kk), &sm[bsel][1][u][wave * 512])

    // LDS-read macros. RDA: A i-pair (2*pr, 2*pr+1) from buffer bsel.
    #define RDA(dst, bsel, pr) { \
        _Pragma("unroll") \
        for (int ii = 0; ii < 2; ii++) { \
            int br = wm * 128 + ((pr) * 2 + ii) * 16 + lm; \
            _Pragma("unroll") \
            for (int ks = 0; ks < 2; ks++) \
                dst[ii][ks] = *(const bf16x8*)&sm[bsel][0][br >> 6] \
                    [(br & 63) * 64 + (((ks * 4 + lq) ^ (br & 7)) * 8)]; \
        } }
    #define RDB(bsel) { \
        _Pragma("unroll") \
        for (int j = 0; j < 4; j++) { \
            int br = wn * 64 + j * 16 + lm; \
            _Pragma("unroll") \
            for (int ks = 0; ks < 2; ks++) \
                bq[j][ks] = *(const bf16x8*)&sm[bsel][1][br >> 6] \
                    [(br & 63) * 64 + (((ks * 4 + lq) ^ (br & 7)) * 8)]; \
        } }
    #define MMPH(af, p) { \
        __builtin_amdgcn_s_setprio(1); \
        _Pragma("unroll") \
        for (int ii = 0; ii < 2; ii++) \
            _Pragma("unroll") \
            for (int j = 0; j < 4; j++) { \
                acc[2 * (p) + ii][j] = __builtin_amdgcn_mfma_f32_16x16x32_bf16( \
                    af[ii][0], bq[j][0], acc[2 * (p) + ii][j], 0, 0, 0); \
                acc[2 * (p) + ii][j] = __builtin_amdgcn_mfma_f32_16x16x32_bf16( \
                    af[ii][1], bq[j][1], acc[2 * (p) + ii][j], 0, 0, 0); \
            } \
        __builtin_amdgcn_s_setprio(0); }

    f32x4 acc[8][4];
    #pragma unroll
    for (int i = 0; i < 8; i++)
        #pragma unroll
        for (int j = 0; j < 4; j++)
            #pragma unroll
            for (int rr = 0; rr < 4; rr++) acc[i][j][rr] = 0.0f;

    const int NT = Kc >> 6;
    // prologue, exact issue order (oldest->newest) matched to vmcnt(4) math:
    // [0.b0 0.b1][0.a0 0.a2][0.a1 0.a3][0.b2 0.b3][1.b0 1.b1][1.a0 1.a2]
    STB(0, 0, 0); STB(0, 1, 0); STA(0, 0, 0); STA(0, 2, 0);
    STA(0, 1, 0); STA(0, 3, 0); STB(0, 2, 0); STB(0, 3, 0);
    if (NT > 1) { STB(1, 0, 64); STB(1, 1, 64); STA(1, 0, 64); STA(1, 2, 64); }

    bf16x8 bq[4][2], afA[2][2], afB[2][2];

    for (int t = 0; t < NT; ++t) {
        const int b   = t & 1;
        const int kk1 = (t + 1) * 64;
        const int kk2 = (t + 2) * 64;

        if (t == NT - 1) asm volatile("s_waitcnt vmcnt(0)" ::: "memory");
        else             asm volatile("s_waitcnt vmcnt(4)" ::: "memory");
        __builtin_amdgcn_s_barrier();
        __builtin_amdgcn_sched_barrier(0);

        // ---- phase 0: issue q0+q1 reads, MFMA q0, prefetch q2 reads
        RDB(b);
        RDA(afA, b, 0);
        RDA(afB, b, 1);
        if (t + 1 < NT) { STA(b ^ 1, 1, kk1); STA(b ^ 1, 3, kk1); }
        MMPH(afA, 0);
        RDA(afA, b, 2);
        __builtin_amdgcn_sched_barrier(0);
        __builtin_amdgcn_s_barrier();
        __builtin_amdgcn_sched_barrier(0);

        // ---- phase 1: MFMA q1, prefetch q3 reads
        if (t + 1 < NT) { STB(b ^ 1, 2, kk1); STB(b ^ 1, 3, kk1); }
        MMPH(afB, 1);
        RDA(afB, b, 3);
        __builtin_amdgcn_sched_barrier(0);
        __builtin_amdgcn_s_barrier();
        __builtin_amdgcn_sched_barrier(0);

        // ---- phase 2
        if (t + 2 < NT) { STB(b, 0, kk2); STB(b, 1, kk2); }
        MMPH(afA, 2);
        __builtin_amdgcn_sched_barrier(0);
        __builtin_amdgcn_s_barrier();
        __builtin_amdgcn_sched_barrier(0);

        // ---- phase 3
        if (t + 2 < NT) { STA(b, 0, kk2); STA(b, 2, kk2); }
        MMPH(afB, 3);
        __builtin_amdgcn_sched_barrier(0);
    }
    #undef STA
    #undef STB
    #undef RDA
    #undef RDB
    #undef MMPH

    // epilogue: C/D layout col=lane&15, row=(lane>>4)*4+reg
    const size_t zoff = (size_t)blockIdx.z * (size_t)M * ldc;
    #pragma unroll
    for (int i = 0; i < 8; i++) {
        #pragma unroll
        for (int rr = 0; rr < 4; rr++) {
            int row = row0 + wm * 128 + i * 16 + lq * 4 + rr;
            #pragma unroll
            for (int j = 0; j < 4; j++) {
                int col = col0 + wn * 64 + j * 16 + lm;
                if (col < N) {
                    float v = acc[i][j][rr];
                    if (OBF16)
                        ((unsigned short*)Cout)[(size_t)row * ldc + col] = f2bf(v);
                    else
                        ((float*)Cout)[zoff + (size_t)row * ldc + col] = v;
                }
            }
        }
    }
}

// Sum nsplit partial C buffers; also emit bf16 copy of cols<64 (dt_lo).
__global__ __launch_bounds__(256) void reduce_splitk(
    const float* __restrict__ part, float* __restrict__ C,
    unsigned short* __restrict__ dtlo16, int n, int nsplit)
{
    int i = blockIdx.x * 256 + threadIdx.x;
    if (i >= n) return;
    float s = 0.0f;
    for (int z = 0; z < nsplit; z++) s += part[(size_t)z * n + i];
    C[i] = s;
    int row = i / 96;
    int col = i - row * 96;
    if (col < DTRANK) dtlo16[row * DTRANK + col] = f2bf(s);
}

// Sum 4 fp32 partials, vectorized. n4 = total_floats/4.
__global__ __launch_bounds__(256) void reduce4(
    const float* __restrict__ part, float* __restrict__ out, int n4)
{
    int i = blockIdx.x * 256 + threadIdx.x;
    if (i >= n4) return;
    const f32x4* p = (const f32x4*)part;
    f32x4 s = p[i];
    s += p[i + n4];
    s += p[i + 2 * n4];
    s += p[i + 3 * n4];
    ((f32x4*)out)[i] = s;
}

// conv + silu, register-rolling window along l. Reads bf16 xz (cols 0..2048),
// emits bf16 xc16. grid (8, 64, 2).
__global__ __launch_bounds__(256) void conv_silu_v2(
    const unsigned short* __restrict__ xz16, const float* __restrict__ conv_w,
    const float* __restrict__ conv_b, unsigned short* __restrict__ xc16)
{
    const int tid = threadIdx.x;
    const int d   = blockIdx.x * 256 + tid;
    const int l0  = blockIdx.y * 32;
    const int b   = blockIdx.z;
    const float4 w  = *(const float4*)(conv_w + d * 4);
    const float bias = conv_b[d];
    const int t0 = b * L_SZ + l0;
    const unsigned short* src = xz16 + (size_t)t0 * 4096 + d;

    float r0, r1, r2;
    if (l0 == 0) {
        r0 = r1 = r2 = 0.0f;
    } else {
        r0 = bf2f(src[-3 * 4096]);
        r1 = bf2f(src[-2 * 4096]);
        r2 = bf2f(src[-1 * 4096]);
    }
    #pragma unroll 4
    for (int l = 0; l < 32; l++) {
        float r3 = bf2f(src[(size_t)l * 4096]);
        float acc = bias + r0 * w.x + r1 * w.y + r2 * w.z + r3 * w.w;
        xc16[(size_t)(t0 + l) * DINNER + d] = f2bf(silu_f(acc));
        r0 = r1; r1 = r2; r2 = r3;
    }
}

// ---- Chunked parallel selective scan (CS=32, 1024 blocks) -------------------
// v4: 16 states/thread, packed f32x2 math, fexp2 with folded log2e.
// grid: B * NCH * 8 = 1024; db=blk&7, c=(blk>>3)&63, b=blk>>9.
__global__ __launch_bounds__(256) void scan_pass1(
    const unsigned short* __restrict__ xc16, const float* __restrict__ delta,
    const float* __restrict__ dbc, const float* __restrict__ A_log,
    float* __restrict__ P, float* __restrict__ E)
{
    __shared__ float Bs[CS * DSTATE];
    const int tid = threadIdx.x;
    const int db  = blockIdx.x & 7;
    const int c   = (blockIdx.x >> 3) & (NCH - 1);
    const int b   = blockIdx.x >> 9;
    const int d   = db * 256 + tid;
    const int t0  = b * L_SZ + c * CS;

    for (int idx = tid; idx < CS * DSTATE; idx += 256) {
        int step = idx >> 4, i = idx & 15;
        Bs[idx] = dbc[(t0 + step) * 96 + DTRANK + i];
    }

    f32x2 A2v[8], Er2[8];
    const float* Ap = A_log + d * DSTATE;
    #pragma unroll
    for (int p = 0; p < 8; p++) {
        A2v[p].x = -1.44269504f * __expf(Ap[2 * p]);
        A2v[p].y = -1.44269504f * __expf(Ap[2 * p + 1]);
        Er2[p].x = 0.0f; Er2[p].y = 0.0f;
    }
    float sd = 0.0f;

    const float* dp = delta + (size_t)t0 * DINNER + d;
    const unsigned short* up = xc16 + (size_t)t0 * DINNER + d;

    float dv[4], uv[4];
    #pragma unroll
    for (int q = 0; q < 4; q++) {
        dv[q] = dp[(size_t)q * DINNER];
        uv[q] = bf2f(up[(size_t)q * DINNER]);
    }
    __syncthreads();

    for (int lo = 0; lo < CS; lo += 4) {
        float nd[4], nu[4];
        if (lo + 4 < CS) {
            #pragma unroll
            for (int q = 0; q < 4; q++) {
                nd[q] = dp[(size_t)(lo + 4 + q) * DINNER];
                nu[q] = bf2f(up[(size_t)(lo + 4 + q) * DINNER]);
            }
        }
        #pragma unroll
        for (int q = 0; q < 4; q++) {
            const float dvq = dv[q];
            const float du  = dvq * uv[q];
            sd += dvq;
            const f32x4* Bv = (const f32x4*)&Bs[(lo + q) * DSTATE];
            f32x4 b0 = Bv[0], b1 = Bv[1], b2 = Bv[2], b3 = Bv[3];
            #define P1PAIR(p, bb) { \
                f32x2 m = dvq * A2v[p]; \
                f32x2 e; e.x = fexp2(m.x); e.y = fexp2(m.y); \
                Er2[p] = e * Er2[p] + du * (bb); }
            P1PAIR(0, b0.xy) P1PAIR(1, b0.zw)
            P1PAIR(2, b1.xy) P1PAIR(3, b1.zw)
            P1PAIR(4, b2.xy) P1PAIR(5, b2.zw)
            P1PAIR(6, b3.xy) P1PAIR(7, b3.zw)
            #undef P1PAIR
        }
        #pragma unroll
        for (int q = 0; q < 4; q++) { dv[q] = nd[q]; uv[q] = nu[q]; }
    }

    const long long o = ((long long)((b * NCH + c) * DINNER) + d) * DSTATE;
    #pragma unroll
    for (int w = 0; w < 4; w++) {
        f32x4 pv, ev;
        #pragma unroll
        for (int k = 0; k < 2; k++) {
            int p = w * 2 + k;
            pv[2 * k]     = fexp2(A2v[p].x * sd);
            pv[2 * k + 1] = fexp2(A2v[p].y * sd);
            ev[2 * k]     = Er2[p].x;
            ev[2 * k + 1] = Er2[p].y;
        }
        *(f32x4*)(P + o + w * 4) = pv;
        *(f32x4*)(E + o + w * 4) = ev;
    }
}

__global__ __launch_bounds__(256) void scan_pass2(
    const float* __restrict__ P, float* __restrict__ E)
{
    const int gid  = blockIdx.x * 256 + threadIdx.x;
    const int b    = gid >> 15;
    const int rest = gid & 32767;
    float h = 0.0f;
    for (int c = 0; c < NCH; c++) {
        const long long idx = (long long)(b * NCH + c) * (DINNER * DSTATE) + rest;
        float p = P[idx];
        float e = E[idx];
        E[idx] = h;
        h = p * h + e;
    }
}

// pass3 v4: packed math (see pass1), fused silu(z) gate, bf16 y out.
__global__ __launch_bounds__(256) void scan_pass3(
    const unsigned short* __restrict__ xc16, const float* __restrict__ delta,
    const float* __restrict__ dbc, const float* __restrict__ A_log,
    const float* __restrict__ D_skip, const float* __restrict__ Hin,
    const unsigned short* __restrict__ xz16, unsigned short* __restrict__ y16)
{
    __shared__ float BCs[CS * 2 * DSTATE];
    const int tid = threadIdx.x;
    const int db  = blockIdx.x & 7;
    const int c   = (blockIdx.x >> 3) & (NCH - 1);
    const int b   = blockIdx.x >> 9;
    const int d   = db * 256 + tid;
    const int t0  = b * L_SZ + c * CS;

    for (int idx = tid; idx < CS * 2 * DSTATE; idx += 256) {
        int step = idx >> 5, i = idx & 31;
        BCs[idx] = dbc[(t0 + step) * 96 + DTRANK + i];
    }

    f32x2 A2v[8], h2[8];
    const float* Ap = A_log + d * DSTATE;
    const long long o = ((long long)((b * NCH + c) * DINNER) + d) * DSTATE;
    #pragma unroll
    for (int p = 0; p < 8; p++) {
        A2v[p].x = -1.44269504f * __expf(Ap[2 * p]);
        A2v[p].y = -1.44269504f * __expf(Ap[2 * p + 1]);
        h2[p].x = Hin[o + 2 * p];
        h2[p].y = Hin[o + 2 * p + 1];
    }
    const float Dv = D_skip[d];

    const float* dp = delta + (size_t)t0 * DINNER + d;
    const unsigned short* up = xc16 + (size_t)t0 * DINNER + d;
    const unsigned short* zp = xz16 + (size_t)t0 * 4096 + DINNER + d;
    unsigned short* yp = y16 + (size_t)t0 * DINNER + d;

    float dv[4], uv[4], zv[4];
    #pragma unroll
    for (int q = 0; q < 4; q++) {
        dv[q] = dp[(size_t)q * DINNER];
        uv[q] = bf2f(up[(size_t)q * DINNER]);
        zv[q] = bf2f(zp[(size_t)q * 4096]);
    }
    __syncthreads();

    for (int lo = 0; lo < CS; lo += 4) {
        float nd[4], nu[4], nz[4];
        if (lo + 4 < CS) {
            #pragma unroll
            for (int q = 0; q < 4; q++) {
                nd[q] = dp[(size_t)(lo + 4 + q) * DINNER];
                nu[q] = bf2f(up[(size_t)(lo + 4 + q) * DINNER]);
                nz[q] = bf2f(zp[(size_t)(lo + 4 + q) * 4096]);
            }
        }
        #pragma unroll
        for (int q = 0; q < 4; q++) {
            const float dvq = dv[q];
            const float uvq = uv[q];
            const float du  = dvq * uvq;
            const f32x4* Bv = (const f32x4*)&BCs[(lo + q) * 32];
            f32x4 b0 = Bv[0], b1 = Bv[1], b2 = Bv[2], b3 = Bv[3];
            f32x4 c0 = Bv[4], c1 = Bv[5], c2 = Bv[6], c3 = Bv[7];
            f32x2 y0; y0.x = 0.0f; y0.y = 0.0f;
            f32x2 y1; y1.x = 0.0f; y1.y = 0.0f;
            #define P3PAIR(p, bb, cc, ya) { \
                f32x2 m = dvq * A2v[p]; \
                f32x2 e; e.x = fexp2(m.x); e.y = fexp2(m.y); \
                h2[p] = e * h2[p] + du * (bb); \
                ya = ya + h2[p] * (cc); }
            P3PAIR(0, b0.xy, c0.xy, y0) P3PAIR(1, b0.zw, c0.zw, y1)
            P3PAIR(2, b1.xy, c1.xy, y0) P3PAIR(3, b1.zw, c1.zw, y1)
            P3PAIR(4, b2.xy, c2.xy, y0) P3PAIR(5, b2.zw, c2.zw, y1)
            P3PAIR(6, b3.xy, c3.xy, y0) P3PAIR(7, b3.zw, c3.zw, y1)
            #undef P3PAIR
            f32x2 ys = y0 + y1;
            float yv = ys.x + ys.y;
            yp[(size_t)(lo + q) * DINNER] = f2bf((uvq * Dv + yv) * silu_f(zv[q]));
        }
        #pragma unroll
        for (int q = 0; q < 4; q++) { dv[q] = nd[q]; uv[q] = nu[q]; zv[q] = nz[q]; }
    }
}

extern "C" void kernel_launch(void* const* d_in, const int* in_sizes, int n_in,
                              void* d_out, int out_size, void* d_ws, size_t ws_size,
                              hipStream_t stream) {
    const float* x       = (const float*)d_in[0];
    const float* W_in    = (const float*)d_in[1];
    const float* conv_w  = (const float*)d_in[2];
    const float* conv_b  = (const float*)d_in[3];
    const float* W_xproj = (const float*)d_in[4];
    const float* W_dt    = (const float*)d_in[5];
    const float* b_dt    = (const float*)d_in[6];
    const float* A_log   = (const float*)d_in[7];
    const float* D_skip  = (const float*)d_in[8];
    const float* W_out   = (const float*)d_in[9];
    float* out = (float*)d_out;

    // workspace layout, float units (141 MB). Aliases (dead-before-reuse):
    //   parts (dead after reduce) shares Pbuf (written at pass1)
    //   x16 (dead after gemm1)    shares yb16 (written at pass3)
    //   parts6 (GEMM6 split-K partials, 64MB) spans delta..Pbuf — all dead
    //   after pass3; GEMM6/reduce4 run after pass3. 16777216 f exactly. ✓
    float* ws = (float*)d_ws;
    unsigned short* xz16   = (unsigned short*)ws;              // [0 .. 8388608) f
    unsigned short* xc16   = (unsigned short*)(ws +  8388608); // [.. 12582912) f
    float* dbc             = ws + 12582912;                    // [.. 12976128) f
    unsigned short* dtlo16 = (unsigned short*)(ws + 12976128); // [.. 13107200) f
    float* delta           = ws + 13107200;                    // [.. 21495808) f
    float* Ebuf            = ws + 21495808;                    // [.. 25690112) f : 2*64*2048*16
    float* Pbuf            = ws + 25690112;                    // [.. 29884416) f : 2*64*2048*16
    float* parts           = Pbuf;                             //   alias, 3145728 f < 4194304 ✓
    float* parts6          = delta;                            //   alias, 4*4096*1024 = 16777216 f ✓
    unsigned short* yb16   = (unsigned short*)(ws + 29884416); // [.. 31981568) f
    unsigned short* x16    = yb16;                             //   alias
    unsigned short* W_inT    = (unsigned short*)(ws + 31981568); // [.. 34078720) f
    unsigned short* W_xprojT = (unsigned short*)(ws + 34078720); // [.. 34177024) f
    unsigned short* W_dtT    = (unsigned short*)(ws + 34177024); // [.. 34242560) f
    unsigned short* W_outT   = (unsigned short*)(ws + 34242560); // [.. 35291136) f

    const int MT = 4096;  // B*L tokens

    transpose_cast<<<dim3(128, 32), 256, 0, stream>>>(W_in,    W_inT,    1024, 4096);
    transpose_cast<<<dim3(  3, 64), 256, 0, stream>>>(W_xproj, W_xprojT, 2048,   96);
    transpose_cast<<<dim3( 64,  2), 256, 0, stream>>>(W_dt,    W_dtT,      64, 2048);
    transpose_cast<<<dim3( 32, 64), 256, 0, stream>>>(W_out,   W_outT,   2048, 1024);
    cast_bf16<<<dim3(2048), 256, 0, stream>>>(x, x16, 524288);

    // 1) xz = x @ W_in              (4096 x 4096, K=1024) -> bf16, 8-phase v2
    gemm_8ph<1><<<dim3(256), 512, 0, stream>>>(
        x16, W_inT, xz16, MT, 4096, 1024, 1024, 4096, 1024);

    // 2) xc16 = silu(causal_dwconv(xin) + b)
    conv_silu_v2<<<dim3(8, 64, 2), 256, 0, stream>>>(xz16, conv_w, conv_b, xc16);

    // 3) dbc = xc @ W_xproj         (4096 x 96, K=2048) — split-K x8
    gemm_bt_lds<0, 0><<<dim3(1, 32, 8), 256, 0, stream>>>(
        xc16, W_xprojT, parts, nullptr, MT, 96, 2048, 2048, 2048, 96, 256);
    reduce_splitk<<<dim3(1536), 256, 0, stream>>>(parts, dbc, dtlo16, MT * 96, 8);

    // 4) delta = softplus(dt_lo @ W_dt + b_dt)  (4096 x 2048, K=64) — fast softplus
    gemm_bt_lds<1, 0><<<dim3(16, 32), 256, 0, stream>>>(
        dtlo16, W_dtT, delta, b_dt, MT, 2048, 64, 64, 64, 2048, 64);

    // 5) chunked selective scan + fused gate (bf16 y out), packed math v4
    scan_pass1<<<dim3(1024), 256, 0, stream>>>(xc16, delta, dbc, A_log, Pbuf, Ebuf);
    scan_pass2<<<dim3(256), 256, 0, stream>>>(Pbuf, Ebuf);
    scan_pass3<<<dim3(1024), 256, 0, stream>>>(xc16, delta, dbc, A_log, D_skip,
                                               Ebuf, xz16, yb16);

    // 6) out = y @ W_out   (4096 x 1024, K=2048) — 8-phase v2, split-K x4
    //    ldb = 2048 (W_outT row stride = K).
    gemm_8ph<0><<<dim3(64, 1, 4), 512, 0, stream>>>(
        yb16, W_outT, parts6, MT, 1024, 2048, 2048, 1024, 512);
    reduce4<<<dim3(4096), 256, 0, stream>>>(parts6, out, MT * 1024 / 4);
}